// Round 11
// baseline (217.137 us; speedup 1.0000x reference)
//
#include <hip/hip_runtime.h>
#include <stdint.h>

#define B_ 2
#define S_ 1024
#define D_ 768
#define NH_ 12
#define DH_ 64
#define HID_ 1536
#define G_ 4
#define EPG_ 2
#define E_ 8
#define NTOK (B_*S_)
#define NGRP (B_*NH_*16)   // 384 (bh x qb64) groups
#define KSPLIT 3

typedef unsigned short u16;
typedef unsigned int u32;
typedef __bf16 bf16x8 __attribute__((ext_vector_type(8)));
typedef float f32x4 __attribute__((ext_vector_type(4)));
typedef u16 u16x4 __attribute__((ext_vector_type(4)));
typedef u16 u16x8 __attribute__((ext_vector_type(8)));
typedef u32 u32x4 __attribute__((ext_vector_type(4)));

struct BfPair { u16 hi, lo; };

__device__ __forceinline__ u16 f2bf(float f){
  unsigned u = __builtin_bit_cast(unsigned, f);
  u += 0x7FFFu + ((u >> 16) & 1u);
  return (u16)(u >> 16);
}
__device__ __forceinline__ float bf2f(u16 h){
  unsigned u = ((unsigned)h) << 16;
  return __builtin_bit_cast(float, u);
}
__device__ __forceinline__ BfPair split_bf(float v){
  BfPair p;
  p.hi = f2bf(v);
  p.lo = f2bf(v - bf2f(p.hi));
  return p;
}
__device__ __forceinline__ float gelu_tanh(float x){
  float t = 0.7978845608028654f * (x + 0.044715f * x * x * x);
  float e = __expf(2.f * t);
  float th = 1.f - 2.f / (e + 1.f);
  return 0.5f * x * (1.f + th);
}
__device__ __forceinline__ void gload_lds16(const void* g, void* l){
  __builtin_amdgcn_global_load_lds(
      (const __attribute__((address_space(1))) void*)g,
      (__attribute__((address_space(3))) void*)l, 16, 0, 0);
}

// ---------------- fused weight prep ----------------
__global__ __launch_bounds__(256) void k_prep(
    const float* __restrict__ in_proj_w, const float* __restrict__ out_proj_w,
    const float* __restrict__ W1, const float* __restrict__ W2,
    u16* __restrict__ inpTh, u16* __restrict__ inpTl,
    u16* __restrict__ outpTh, u16* __restrict__ outpTl,
    u16* __restrict__ W1t, u16* __restrict__ W2t){
  __shared__ float tile[32][33];
  int bid = blockIdx.x, t = threadIdx.x;
  if (bid < 2304){
    const float* src; u16 *dh, *dl; int i;
    if (bid < 1728){ src = in_proj_w; dh = inpTh; dl = inpTl; i = bid * 256 + t; }
    else           { src = out_proj_w; dh = outpTh; dl = outpTl; i = (bid - 1728) * 256 + t; }
    float4 v = ((const float4*)src)[i];
    u16x4 oh, ol;
    BfPair p0 = split_bf(v.x), p1 = split_bf(v.y), p2 = split_bf(v.z), p3 = split_bf(v.w);
    oh.x = p0.hi; ol.x = p0.lo; oh.y = p1.hi; ol.y = p1.lo;
    oh.z = p2.hi; ol.z = p2.lo; oh.w = p3.hi; ol.w = p3.lo;
    ((u16x4*)dh)[i] = oh;
    ((u16x4*)dl)[i] = ol;
  } else {
    const float* src; u16* dst; int R, C, cx, cy, e;
    if (bid < 11520){
      int r = bid - 2304; e = r / 1152; r %= 1152;
      R = D_; C = HID_; cx = r % 48; cy = r / 48;
      src = W1; dst = W1t;
    } else {
      int r = bid - 11520; e = r / 1152; r %= 1152;
      R = HID_; C = D_; cx = r % 24; cy = r / 24;
      src = W2; dst = W2t;
    }
    const float* s = src + (size_t)e * R * C;
    u16* d = dst + (size_t)e * R * C;
    int c0 = cx * 32, r0 = cy * 32;
    int tx = t & 31, ty = t >> 5;
    #pragma unroll
    for (int i = 0; i < 32; i += 8)
      tile[ty + i][tx] = s[(size_t)(r0 + ty + i) * C + c0 + tx];
    __syncthreads();
    #pragma unroll
    for (int i = 0; i < 32; i += 8)
      d[(size_t)(c0 + ty + i) * R + r0 + tx] = f2bf(tile[tx][ty + i]);
  }
}

// ---------------- layernorm ----------------
__global__ __launch_bounds__(256) void k_layernorm(
    const float* __restrict__ x, const float* __restrict__ w, const float* __restrict__ b,
    u16* __restrict__ oh, u16* __restrict__ ol, float* __restrict__ of){
  int row = blockIdx.x;
  const float* xr = x + (size_t)row * D_;
  int t = threadIdx.x;
  float v0 = xr[t], v1 = xr[t + 256], v2 = xr[t + 512];
  float s = v0 + v1 + v2;
  float sq = v0 * v0 + v1 * v1 + v2 * v2;
  #pragma unroll
  for (int m = 1; m < 64; m <<= 1){ s += __shfl_xor(s, m); sq += __shfl_xor(sq, m); }
  __shared__ float ls[4], lq[4];
  int wid = t >> 6;
  if ((t & 63) == 0){ ls[wid] = s; lq[wid] = sq; }
  __syncthreads();
  s = ls[0] + ls[1] + ls[2] + ls[3];
  sq = lq[0] + lq[1] + lq[2] + lq[3];
  float mean = s * (1.f / D_);
  float var = sq * (1.f / D_) - mean * mean;
  float rstd = rsqrtf(var + 1e-5f);
  #pragma unroll
  for (int i = 0; i < 3; i++){
    int dcol = t + i * 256;
    float v = (i == 0 ? v0 : (i == 1 ? v1 : v2));
    float y = (v - mean) * rstd * w[dcol] + b[dcol];
    BfPair p = split_bf(y);
    oh[(size_t)row * D_ + dcol] = p.hi;
    if (ol) ol[(size_t)row * D_ + dcol] = p.lo;
    if (of) of[(size_t)row * D_ + dcol] = y;
  }
}

// ------- pipelined split-precision GEMM 128x64 (BK=32, swizzled ^row&3) -------
// EPI 0: qkv mode — Q/K cols -> split bf16 to outh/outl; V cols -> transposed into vth/vtl.
// EPI 1: f32 + resid.
template<int EPI>
__global__ __launch_bounds__(256) void k_gemm3(
    const u16* __restrict__ Ah, const u16* __restrict__ Al,
    const u16* __restrict__ Bh, const u16* __restrict__ Bl,
    const float* __restrict__ bias, const float* __restrict__ resid,
    u16* __restrict__ outh, u16* __restrict__ outl, float* __restrict__ outf,
    u16* __restrict__ vth, u16* __restrict__ vtl,
    int M, int N, int K){
  __shared__ alignas(16) u16 Ash[2][128 * 32];
  __shared__ alignas(16) u16 Asl[2][128 * 32];
  __shared__ alignas(16) u16 Bsh[2][64 * 32];
  __shared__ alignas(16) u16 Bsl[2][64 * 32];
  int m0 = blockIdx.x * 128, n0 = blockIdx.y * 64;
  int tid = threadIdx.x, w = tid >> 6, l = tid & 63;
  f32x4 acc[2][4];
  #pragma unroll
  for (int i = 0; i < 2; i++)
    #pragma unroll
    for (int j = 0; j < 4; j++) acc[i][j] = f32x4{0.f, 0.f, 0.f, 0.f};
  int srow = l >> 2;
  int scol = 8 * ((l & 3) ^ ((l >> 2) & 3));
  const u16* gAh0 = Ah + (size_t)(m0 + w * 32 + srow) * K + scol;
  const u16* gAh1 = gAh0 + (size_t)16 * K;
  const u16* gAl0 = Al + (size_t)(m0 + w * 32 + srow) * K + scol;
  const u16* gAl1 = gAl0 + (size_t)16 * K;
  const u16* gBh = Bh + (size_t)(n0 + w * 16 + srow) * K + scol;
  const u16* gBl = Bl + (size_t)(n0 + w * 16 + srow) * K + scol;
  int dA0 = (w * 32) * 32, dA1 = (w * 32 + 16) * 32, dB = (w * 16) * 32;
  auto STAGE = [&](int buf, int k0){
    gload_lds16(gAh0 + k0, &Ash[buf][dA0]);
    gload_lds16(gAh1 + k0, &Ash[buf][dA1]);
    gload_lds16(gAl0 + k0, &Asl[buf][dA0]);
    gload_lds16(gAl1 + k0, &Asl[buf][dA1]);
    gload_lds16(gBh + k0, &Bsh[buf][dB]);
    gload_lds16(gBl + k0, &Bsl[buf][dB]);
  };
  STAGE(0, 0);
  __syncthreads();
  int nk = K / 32;
  int ca = (l >> 4) ^ (l & 3);
  int ai0 = (w * 32 + (l & 15)) * 32 + 8 * ca;
  int ai1 = ai0 + 16 * 32;
  for (int t = 0; t < nk; t++){
    int cur = t & 1;
    if (t + 1 < nk) STAGE(cur ^ 1, (t + 1) * 32);
    bf16x8 afh[2], afl[2], bfh[4], bfl[4];
    afh[0] = *(const bf16x8*)&Ash[cur][ai0];
    afh[1] = *(const bf16x8*)&Ash[cur][ai1];
    afl[0] = *(const bf16x8*)&Asl[cur][ai0];
    afl[1] = *(const bf16x8*)&Asl[cur][ai1];
    #pragma unroll
    for (int ni = 0; ni < 4; ni++){
      int bi = (ni * 16 + (l & 15)) * 32 + 8 * ca;
      bfh[ni] = *(const bf16x8*)&Bsh[cur][bi];
      bfl[ni] = *(const bf16x8*)&Bsl[cur][bi];
    }
    #pragma unroll
    for (int mi = 0; mi < 2; mi++)
      #pragma unroll
      for (int ni = 0; ni < 4; ni++){
        acc[mi][ni] = __builtin_amdgcn_mfma_f32_16x16x32_bf16(afh[mi], bfh[ni], acc[mi][ni], 0, 0, 0);
        acc[mi][ni] = __builtin_amdgcn_mfma_f32_16x16x32_bf16(afh[mi], bfl[ni], acc[mi][ni], 0, 0, 0);
        acc[mi][ni] = __builtin_amdgcn_mfma_f32_16x16x32_bf16(afl[mi], bfh[ni], acc[mi][ni], 0, 0, 0);
      }
    __syncthreads();
  }
  int r4 = (l >> 4) * 4, cc = l & 15;
  if (EPI == 0 && n0 >= 2 * D_){
    // V columns: transpose 128(tokens) x 64(d) tile through LDS -> vt [bh*64+d][s]
    int hh = (n0 - 2 * D_) >> 6;
    int bb = m0 / S_;
    int bhl = bb * NH_ + hh;
    int sg0 = m0 % S_;
    u16* VhL = (u16*)&Ash[0][0];   // viewed as [64][128]
    u16* VlL = (u16*)&Asl[0][0];
    #pragma unroll
    for (int mi = 0; mi < 2; mi++){
      #pragma unroll
      for (int ni = 0; ni < 4; ni++){
        int d = ni * 16 + cc;
        float bv = bias ? bias[n0 + d] : 0.f;
        int sl = w * 32 + mi * 16 + r4;
        u16x4 h4, l4;
        #pragma unroll
        for (int r = 0; r < 4; r++){
          BfPair p = split_bf(acc[mi][ni][r] + bv);
          h4[r] = p.hi; l4[r] = p.lo;
        }
        *(u16x4*)&VhL[d * 128 + sl] = h4;
        *(u16x4*)&VlL[d * 128 + sl] = l4;
      }
    }
    __syncthreads();
    for (int i = tid; i < 64 * 16; i += 256){
      int d = i >> 4, s8 = (i & 15) * 8;
      size_t go = ((size_t)bhl * DH_ + d) * S_ + sg0 + s8;
      *(u16x8*)&vth[go] = *(const u16x8*)&VhL[d * 128 + s8];
      *(u16x8*)&vtl[go] = *(const u16x8*)&VlL[d * 128 + s8];
    }
    return;
  }
  #pragma unroll
  for (int mi = 0; mi < 2; mi++){
    #pragma unroll
    for (int ni = 0; ni < 4; ni++){
      int col = n0 + ni * 16 + cc;
      float bv = bias ? bias[col] : 0.f;
      #pragma unroll
      for (int r = 0; r < 4; r++){
        int row = m0 + w * 32 + mi * 16 + r4 + r;
        float v = acc[mi][ni][r] + bv;
        if (EPI == 0){
          BfPair p = split_bf(v);
          outh[(size_t)row * N + col] = p.hi;
          outl[(size_t)row * N + col] = p.lo;
        } else {
          outf[(size_t)row * N + col] = v + resid[(size_t)row * N + col];
        }
      }
    }
  }
}

// ------- split-precision flash attention, QBLK=128 (32 q/wave), split-K x3, KVBLK=32 -------
// grid (bh=24, qb=8, ks=3). Each wave owns two 16-q fragments sharing K/V LDS reads.
__global__ __launch_bounds__(256) void k_attn3(
    const u16* __restrict__ qkvh, const u16* __restrict__ qkvl,
    const u16* __restrict__ vth, const u16* __restrict__ vtl,
    float* __restrict__ po0, float* __restrict__ po1, float* __restrict__ po2,
    float* __restrict__ pm, float* __restrict__ plsum){
  __shared__ alignas(16) u16 Ksh[2][32 * 64];
  __shared__ alignas(16) u16 Ksl[2][32 * 64];
  __shared__ alignas(16) u16 Vsh[2][64 * 32];
  __shared__ alignas(16) u16 Vsl[2][64 * 32];
  int bh = blockIdx.x, qb = blockIdx.y, ks = blockIdx.z;
  int b = bh / NH_, h = bh % NH_;
  int tid = threadIdx.x, w = tid >> 6, l = tid & 63;
  const int RS = 3 * D_;
  // Q fragments for two 16-row groups: rows qb*128 + w*32 + G*16 + (l&15)
  bf16x8 aqh[2][2], aql[2][2];
  #pragma unroll
  for (int G = 0; G < 2; G++){
    size_t qoff = (size_t)(b * S_ + qb * 128 + w * 32 + G * 16 + (l & 15)) * RS + h * DH_ + 8 * (l >> 4);
    aqh[G][0] = *(const bf16x8*)(qkvh + qoff); aqh[G][1] = *(const bf16x8*)(qkvh + qoff + 32);
    aql[G][0] = *(const bf16x8*)(qkvl + qoff); aql[G][1] = *(const bf16x8*)(qkvl + qoff + 32);
  }
  f32x4 oacc[2][4];
  #pragma unroll
  for (int G = 0; G < 2; G++)
    #pragma unroll
    for (int i = 0; i < 4; i++) oacc[G][i] = f32x4{0.f, 0.f, 0.f, 0.f};
  float mrun[2] = {-1e30f, -1e30f}, lrun[2] = {0.f, 0.f};

  size_t koff = (size_t)(b * S_ + w * 8 + (l >> 3)) * RS + D_ + h * DH_ + 8 * ((l & 7) ^ (l >> 3));
  const u16* Kgh = qkvh + koff;
  const u16* Kgl = qkvl + koff;
  size_t voff = ((size_t)bh * DH_ + w * 16 + (l >> 2)) * S_ + 8 * ((l & 3) ^ ((l >> 2) & 3));
  const u16* Vgh = vth + voff;
  const u16* Vgl = vtl + voff;
  int wdst = w * 512;

  auto STAGE = [&](int buf, int akt){
    gload_lds16(Kgh + (size_t)(akt * 32) * RS, &Ksh[buf][wdst]);
    gload_lds16(Kgl + (size_t)(akt * 32) * RS, &Ksl[buf][wdst]);
    gload_lds16(Vgh + akt * 32, &Vsh[buf][wdst]);
    gload_lds16(Vgl + akt * 32, &Vsl[buf][wdst]);
  };
  int kt0 = (ks * 32) / KSPLIT;
  int ktE = ((ks + 1) * 32) / KSPLIT;
  STAGE(0, kt0);
  __syncthreads();

  int ck0 = (l >> 4) ^ (l & 7);
  int ck1 = ck0 ^ 4;
  int cv = (l >> 4) ^ (l & 3);
  int s1 = (l & 15) | ((l & 16) << 1);
  int s2 = s1 + 16;
  bool up = (l & 32) != 0;

  for (int kt = kt0; kt < ktE; kt++){
    int cur = (kt - kt0) & 1;
    if (kt + 1 < ktE) STAGE(cur ^ 1, kt + 1);
    // swapped QK^T for both q-groups, sharing K fragment reads
    f32x4 st[2][2];
    #pragma unroll
    for (int nt = 0; nt < 2; nt++){
      int rbase = (nt * 16 + (l & 15)) * 64;
      bf16x8 kh0 = *(const bf16x8*)&Ksh[cur][rbase + 8 * ck0];
      bf16x8 kh1 = *(const bf16x8*)&Ksh[cur][rbase + 8 * ck1];
      bf16x8 kl0 = *(const bf16x8*)&Ksl[cur][rbase + 8 * ck0];
      bf16x8 kl1 = *(const bf16x8*)&Ksl[cur][rbase + 8 * ck1];
      #pragma unroll
      for (int G = 0; G < 2; G++){
        f32x4 c = f32x4{0.f, 0.f, 0.f, 0.f};
        c = __builtin_amdgcn_mfma_f32_16x16x32_bf16(kh0, aqh[G][0], c, 0, 0, 0);
        c = __builtin_amdgcn_mfma_f32_16x16x32_bf16(kh1, aqh[G][1], c, 0, 0, 0);
        c = __builtin_amdgcn_mfma_f32_16x16x32_bf16(kh0, aql[G][0], c, 0, 0, 0);
        c = __builtin_amdgcn_mfma_f32_16x16x32_bf16(kh1, aql[G][1], c, 0, 0, 0);
        c = __builtin_amdgcn_mfma_f32_16x16x32_bf16(kl0, aqh[G][0], c, 0, 0, 0);
        c = __builtin_amdgcn_mfma_f32_16x16x32_bf16(kl1, aqh[G][1], c, 0, 0, 0);
        st[G][nt] = c;
      }
    }
    // per-group in-register online softmax + P fragment prep
    bf16x8 pah[2], pal[2];
    #pragma unroll
    for (int G = 0; G < 2; G++){
      float mx = fmaxf(fmaxf(fmaxf(st[G][0][0], st[G][0][1]), fmaxf(st[G][0][2], st[G][0][3])),
                       fmaxf(fmaxf(st[G][1][0], st[G][1][1]), fmaxf(st[G][1][2], st[G][1][3])));
      mx = fmaxf(mx, __shfl_xor(mx, 16));
      mx = fmaxf(mx, __shfl_xor(mx, 32));
      mx *= 0.125f;
      if (!__all(mx <= mrun[G])){
        float mnew = fmaxf(mrun[G], mx);
        float alpha = __expf(mrun[G] - mnew);
        lrun[G] *= alpha;
        #pragma unroll
        for (int r = 0; r < 4; r++){
          float ar = __shfl(alpha, (l & 48) | (((l >> 4) << 2) + r));
          oacc[G][0][r] *= ar; oacc[G][1][r] *= ar; oacc[G][2][r] *= ar; oacc[G][3][r] *= ar;
        }
        mrun[G] = mnew;
      }
      float p[8]; float sum = 0.f;
      #pragma unroll
      for (int j = 0; j < 8; j++){
        p[j] = __expf(st[G][j >> 2][j & 3] * 0.125f - mrun[G]);
        sum += p[j];
      }
      sum += __shfl_xor(sum, 16);
      sum += __shfl_xor(sum, 32);
      lrun[G] += sum;
      u32 pkh[4], pkl[4];
      #pragma unroll
      for (int i = 0; i < 4; i++){
        BfPair a = split_bf(p[2 * i]), bb = split_bf(p[2 * i + 1]);
        pkh[i] = (u32)a.hi | ((u32)bb.hi << 16);
        pkl[i] = (u32)a.lo | ((u32)bb.lo << 16);
      }
      u32 ah0 = __shfl((int)pkh[0], s1), ah1 = __shfl((int)pkh[1], s1);
      u32 ah2 = __shfl((int)pkh[2], s1), ah3 = __shfl((int)pkh[3], s1);
      u32 bh0 = __shfl((int)pkh[0], s2), bh1 = __shfl((int)pkh[1], s2);
      u32 bh2 = __shfl((int)pkh[2], s2), bh3 = __shfl((int)pkh[3], s2);
      u32 al0 = __shfl((int)pkl[0], s1), al1 = __shfl((int)pkl[1], s1);
      u32 al2 = __shfl((int)pkl[2], s1), al3 = __shfl((int)pkl[3], s1);
      u32 bl0 = __shfl((int)pkl[0], s2), bl1 = __shfl((int)pkl[1], s2);
      u32 bl2 = __shfl((int)pkl[2], s2), bl3 = __shfl((int)pkl[3], s2);
      u32x4 fh, fl;
      fh.x = up ? ah2 : ah0; fh.y = up ? ah3 : ah1; fh.z = up ? bh2 : bh0; fh.w = up ? bh3 : bh1;
      fl.x = up ? al2 : al0; fl.y = up ? al3 : al1; fl.z = up ? bl2 : bl0; fl.w = up ? bl3 : bl1;
      pah[G] = __builtin_bit_cast(bf16x8, fh);
      pal[G] = __builtin_bit_cast(bf16x8, fl);
    }
    // PV for both q-groups, sharing V fragment reads
    #pragma unroll
    for (int dt = 0; dt < 4; dt++){
      int vb = (dt * 16 + (l & 15)) * 32 + 8 * cv;
      bf16x8 bvh = *(const bf16x8*)&Vsh[cur][vb];
      bf16x8 bvl = *(const bf16x8*)&Vsl[cur][vb];
      #pragma unroll
      for (int G = 0; G < 2; G++){
        oacc[G][dt] = __builtin_amdgcn_mfma_f32_16x16x32_bf16(pah[G], bvh, oacc[G][dt], 0, 0, 0);
        oacc[G][dt] = __builtin_amdgcn_mfma_f32_16x16x32_bf16(pah[G], bvl, oacc[G][dt], 0, 0, 0);
        oacc[G][dt] = __builtin_amdgcn_mfma_f32_16x16x32_bf16(pal[G], bvh, oacc[G][dt], 0, 0, 0);
      }
    }
    __syncthreads();
  }
  // partial epilogue: unnormalized O + m + l (po indexed by bh*1024 + global-q-in-seq)
  float* po = (ks == 0) ? po0 : ((ks == 1) ? po1 : po2);
  #pragma unroll
  for (int G = 0; G < 2; G++)
    #pragma unroll
    for (int dt = 0; dt < 4; dt++)
      #pragma unroll
      for (int r = 0; r < 4; r++){
        int qg = qb * 128 + w * 32 + G * 16 + (l >> 4) * 4 + r;
        int d = dt * 16 + (l & 15);
        po[((size_t)(bh * 1024 + qg)) * 64 + d] = oacc[G][dt][r];
      }
  if (l < 16){
    #pragma unroll
    for (int G = 0; G < 2; G++){
      int qg = qb * 128 + w * 32 + G * 16 + l;
      pm[ks * (NGRP * 64) + bh * 1024 + qg] = mrun[G];
      plsum[ks * (NGRP * 64) + bh * 1024 + qg] = lrun[G];
    }
  }
}

// ---------------- attn split-K merge (3-way) -> split bf16 attn output ----------------
__global__ __launch_bounds__(256) void k_attn_merge(
    const float* __restrict__ po0, const float* __restrict__ po1, const float* __restrict__ po2,
    const float* __restrict__ pm, const float* __restrict__ plsum,
    u16* __restrict__ oh, u16* __restrict__ ol){
  int bh = blockIdx.x, qb = blockIdx.y;
  int b = bh / NH_, h = bh % NH_;
  int g = bh * 16 + qb;
  int t = threadIdx.x;
  int q = t >> 2, d0 = (t & 3) * 16;
  float m0 = pm[g * 64 + q];
  float m1 = pm[(NGRP + g) * 64 + q];
  float m2 = pm[(2 * NGRP + g) * 64 + q];
  float l0 = plsum[g * 64 + q];
  float l1 = plsum[(NGRP + g) * 64 + q];
  float l2 = plsum[(2 * NGRP + g) * 64 + q];
  float M = fmaxf(fmaxf(m0, m1), m2);
  float a0 = __expf(m0 - M), a1 = __expf(m1 - M), a2 = __expf(m2 - M);
  float rcp = 1.f / (l0 * a0 + l1 * a1 + l2 * a2);
  size_t base = ((size_t)(g * 64 + q)) * 64 + d0;
  size_t orow = (size_t)(b * S_ + qb * 64 + q) * D_ + h * DH_ + d0;
  #pragma unroll
  for (int j = 0; j < 16; j++){
    float v = (po0[base + j] * a0 + po1[base + j] * a1 + po2[base + j] * a2) * rcp;
    BfPair p = split_bf(v);
    oh[orow + j] = p.hi;
    ol[orow + j] = p.lo;
  }
}

// ---------------- router (f32, no atomics) ----------------
__global__ __launch_bounds__(256) void k_router(
    const float* __restrict__ h2f, const float* __restrict__ Wg, const float* __restrict__ bg,
    const float* __restrict__ We, const float* __restrict__ be,
    int* __restrict__ flat, float* __restrict__ pc){
  int w = threadIdx.x >> 6, l = threadIdx.x & 63;
  int n = blockIdx.x * 4 + w;
  const float* hr = h2f + (size_t)n * D_;
  float pl[4] = {0.f, 0.f, 0.f, 0.f};
  for (int d = l; d < D_; d += 64){
    float hv = hr[d];
    float4 wg = *(const float4*)&Wg[d * 4];
    pl[0] += hv * wg.x; pl[1] += hv * wg.y; pl[2] += hv * wg.z; pl[3] += hv * wg.w;
  }
  #pragma unroll
  for (int m = 1; m < 64; m <<= 1)
    #pragma unroll
    for (int g = 0; g < 4; g++) pl[g] += __shfl_xor(pl[g], m);
  float lg[4];
  #pragma unroll
  for (int g = 0; g < 4; g++) lg[g] = pl[g] + bg[g];
  int gi = 0; float gm = lg[0];
  #pragma unroll
  for (int g = 1; g < 4; g++) if (lg[g] > gm){ gm = lg[g]; gi = g; }
  float gs = 0.f;
  #pragma unroll
  for (int g = 0; g < 4; g++) gs += expf(lg[g] - gm);
  float pg = 1.f / gs;
  float e0 = 0.f, e1 = 0.f;
  for (int d = l; d < D_; d += 64){
    float hv = hr[d];
    float2 we = *(const float2*)&We[((size_t)gi * D_ + d) * 2];
    e0 += hv * we.x; e1 += hv * we.y;
  }
  #pragma unroll
  for (int m = 1; m < 64; m <<= 1){ e0 += __shfl_xor(e0, m); e1 += __shfl_xor(e1, m); }
  e0 += be[gi * 2]; e1 += be[gi * 2 + 1];
  int ei; float pe;
  if (e1 > e0){ ei = 1; pe = 1.f / (1.f + expf(e0 - e1)); }
  else        { ei = 0; pe = 1.f / (1.f + expf(e1 - e0)); }
  if (l == 0){
    flat[n] = gi * 2 + ei;
    pc[n] = pg * pe;
  }
}

// ---------------- single-block bucketing ----------------
__global__ __launch_bounds__(1024) void k_bucket(
    const int* __restrict__ flat, int* __restrict__ moeI, int* __restrict__ order){
  __shared__ int cnt[E_], off[E_], cur[E_];
  int t = threadIdx.x;
  if (t < E_){ cnt[t] = 0; cur[t] = 0; }
  __syncthreads();
  int n0 = t, n1 = t + 1024;
  int f0 = flat[n0], f1 = flat[n1];
  atomicAdd(&cnt[f0], 1);
  atomicAdd(&cnt[f1], 1);
  __syncthreads();
  if (t == 0){
    int s = 0;
    for (int e = 0; e < E_; e++){
      off[e] = s; moeI[16 + e] = s; moeI[e] = cnt[e]; s += cnt[e];
    }
  }
  __syncthreads();
  int p0 = atomicAdd(&cur[f0], 1);
  order[off[f0] + p0] = n0;
  int p1 = atomicAdd(&cur[f1], 1);
  order[off[f1] + p1] = n1;
}

// ------- pipelined grouped GEMM 1 (64x64, BK=64, swizzled ^row&7) -------
__global__ __launch_bounds__(256) void k_moe_gemm1(
    const u16* __restrict__ h2, const u16* __restrict__ W1t, const float* __restrict__ b1,
    const int* __restrict__ order, const int* __restrict__ moeI, u16* __restrict__ hid){
  int e = blockIdx.x, mt = blockIdx.y, nt = blockIdx.z;
  int cnt = moeI[e];
  if (mt * 64 >= cnt) return;
  int off = moeI[16 + e];
  __shared__ alignas(16) u16 As[2][64 * 64];
  __shared__ alignas(16) u16 Bs[2][64 * 64];
  int tid = threadIdx.x, w = tid >> 6, l = tid & 63;
  int wr = w >> 1, wc = w & 1;
  f32x4 acc[2][2];
  #pragma unroll
  for (int i = 0; i < 2; i++)
    #pragma unroll
    for (int j = 0; j < 2; j++) acc[i][j] = f32x4{0.f, 0.f, 0.f, 0.f};
  int r0 = w * 16 + (l >> 3);
  int sch = 8 * ((l & 7) ^ (l >> 3));
  int tokA0 = order[off + min(mt * 64 + r0, cnt - 1)];
  int tokA1 = order[off + min(mt * 64 + r0 + 8, cnt - 1)];
  const u16* gA0 = h2 + (size_t)tokA0 * D_ + sch;
  const u16* gA1 = h2 + (size_t)tokA1 * D_ + sch;
  const u16* gB0 = W1t + (size_t)e * HID_ * D_ + (size_t)(nt * 64 + r0) * D_ + sch;
  const u16* gB1 = gB0 + (size_t)8 * D_;
  int d0 = (w * 16) * 64, d1 = (w * 16 + 8) * 64;
  auto STAGE = [&](int buf, int k0){
    gload_lds16(gA0 + k0, &As[buf][d0]);
    gload_lds16(gA1 + k0, &As[buf][d1]);
    gload_lds16(gB0 + k0, &Bs[buf][d0]);
    gload_lds16(gB1 + k0, &Bs[buf][d1]);
  };
  STAGE(0, 0);
  __syncthreads();
  int c0 = (l >> 4) ^ (l & 7);
  int c1 = ((l >> 4) + 4) ^ (l & 7);
  const int nk = D_ / 64;
  for (int t = 0; t < nk; t++){
    int cur = t & 1;
    if (t + 1 < nk) STAGE(cur ^ 1, (t + 1) * 64);
    bf16x8 af[2][2], bfr[2][2];
    #pragma unroll
    for (int mi = 0; mi < 2; mi++){
      int rbase = (wr * 32 + mi * 16 + (l & 15)) * 64;
      af[mi][0] = *(const bf16x8*)&As[cur][rbase + 8 * c0];
      af[mi][1] = *(const bf16x8*)&As[cur][rbase + 8 * c1];
    }
    #pragma unroll
    for (int ni = 0; ni < 2; ni++){
      int rbase = (wc * 32 + ni * 16 + (l & 15)) * 64;
      bfr[ni][0] = *(const bf16x8*)&Bs[cur][rbase + 8 * c0];
      bfr[ni][1] = *(const bf16x8*)&Bs[cur][rbase + 8 * c1];
    }
    #pragma unroll
    for (int mi = 0; mi < 2; mi++)
      #pragma unroll
      for (int ni = 0; ni < 2; ni++){
        acc[mi][ni] = __builtin_amdgcn_mfma_f32_16x16x32_bf16(af[mi][0], bfr[ni][0], acc[mi][ni], 0, 0, 0);
        acc[mi][ni] = __builtin_amdgcn_mfma_f32_16x16x32_bf16(af[mi][1], bfr[ni][1], acc[mi][ni], 0, 0, 0);
      }
    __syncthreads();
  }
  int r4 = (l >> 4) * 4, cc = l & 15;
  #pragma unroll
  for (int mi = 0; mi < 2; mi++){
    #pragma unroll
    for (int ni = 0; ni < 2; ni++){
      int col = nt * 64 + wc * 32 + ni * 16 + cc;
      float bv = b1[e * HID_ + col];
      #pragma unroll
      for (int r = 0; r < 4; r++){
        int rowl = mt * 64 + wr * 32 + mi * 16 + r4 + r;
        if (rowl < cnt){
          float v = gelu_tanh(acc[mi][ni][r] + bv);
          hid[(size_t)(off + rowl) * HID_ + col] = f2bf(v);
        }
      }
    }
  }
}

// ------- pipelined grouped GEMM 2 (64x64, BK=64, swizzled) -------
__global__ __launch_bounds__(256) void k_moe_gemm2(
    const u16* __restrict__ hid, const u16* __restrict__ W2t, const float* __restrict__ b2,
    const int* __restrict__ order, const int* __restrict__ moeI,
    const float* __restrict__ pc, const float* __restrict__ x2, float* __restrict__ out){
  int e = blockIdx.x, mt = blockIdx.y, nt = blockIdx.z;
  int cnt = moeI[e];
  if (mt * 64 >= cnt) return;
  int off = moeI[16 + e];
  __shared__ alignas(16) u16 As[2][64 * 64];
  __shared__ alignas(16) u16 Bs[2][64 * 64];
  int tid = threadIdx.x, w = tid >> 6, l = tid & 63;
  int wr = w >> 1, wc = w & 1;
  f32x4 acc[2][2];
  #pragma unroll
  for (int i = 0; i < 2; i++)
    #pragma unroll
    for (int j = 0; j < 2; j++) acc[i][j] = f32x4{0.f, 0.f, 0.f, 0.f};
  int r0 = w * 16 + (l >> 3);
  int sch = 8 * ((l & 7) ^ (l >> 3));
  int ar0 = off + min(mt * 64 + r0, cnt - 1);
  int ar1 = off + min(mt * 64 + r0 + 8, cnt - 1);
  const u16* gA0 = hid + (size_t)ar0 * HID_ + sch;
  const u16* gA1 = hid + (size_t)ar1 * HID_ + sch;
  const u16* gB0 = W2t + (size_t)e * D_ * HID_ + (size_t)(nt * 64 + r0) * HID_ + sch;
  const u16* gB1 = gB0 + (size_t)8 * HID_;
  int d0 = (w * 16) * 64, d1 = (w * 16 + 8) * 64;
  auto STAGE = [&](int buf, int k0){
    gload_lds16(gA0 + k0, &As[buf][d0]);
    gload_lds16(gA1 + k0, &As[buf][d1]);
    gload_lds16(gB0 + k0, &Bs[buf][d0]);
    gload_lds16(gB1 + k0, &Bs[buf][d1]);
  };
  STAGE(0, 0);
  __syncthreads();
  int c0 = (l >> 4) ^ (l & 7);
  int c1 = ((l >> 4) + 4) ^ (l & 7);
  const int nk = HID_ / 64;
  for (int t = 0; t < nk; t++){
    int cur = t & 1;
    if (t + 1 < nk) STAGE(cur ^ 1, (t + 1) * 64);
    bf16x8 af[2][2], bfr[2][2];
    #pragma unroll
    for (int mi = 0; mi < 2; mi++){
      int rbase = (wr * 32 + mi * 16 + (l & 15)) * 64;
      af[mi][0] = *(const bf16x8*)&As[cur][rbase + 8 * c0];
      af[mi][1] = *(const bf16x8*)&As[cur][rbase + 8 * c1];
    }
    #pragma unroll
    for (int ni = 0; ni < 2; ni++){
      int rbase = (wc * 32 + ni * 16 + (l & 15)) * 64;
      bfr[ni][0] = *(const bf16x8*)&Bs[cur][rbase + 8 * c0];
      bfr[ni][1] = *(const bf16x8*)&Bs[cur][rbase + 8 * c1];
    }
    #pragma unroll
    for (int mi = 0; mi < 2; mi++)
      #pragma unroll
      for (int ni = 0; ni < 2; ni++){
        acc[mi][ni] = __builtin_amdgcn_mfma_f32_16x16x32_bf16(af[mi][0], bfr[ni][0], acc[mi][ni], 0, 0, 0);
        acc[mi][ni] = __builtin_amdgcn_mfma_f32_16x16x32_bf16(af[mi][1], bfr[ni][1], acc[mi][ni], 0, 0, 0);
      }
    __syncthreads();
  }
  int r4 = (l >> 4) * 4, cc = l & 15;
  #pragma unroll
  for (int mi = 0; mi < 2; mi++){
    #pragma unroll
    for (int r = 0; r < 4; r++){
      int rowl = mt * 64 + wr * 32 + mi * 16 + r4 + r;
      if (rowl < cnt){
        int tok = order[off + rowl];
        float pv = pc[tok];
        #pragma unroll
        for (int ni = 0; ni < 2; ni++){
          int col = nt * 64 + wc * 32 + ni * 16 + cc;
          float v = acc[mi][ni][r] + b2[e * D_ + col];
          out[(size_t)tok * D_ + col] = x2[(size_t)tok * D_ + col] + pv * v;
        }
      }
    }
  }
}

extern "C" void kernel_launch(void* const* d_in, const int* in_sizes, int n_in,
                              void* d_out, int out_size, void* d_ws, size_t ws_size,
                              hipStream_t stream){
  const float* x         = (const float*)d_in[0];
  const float* ln1_w     = (const float*)d_in[1];
  const float* ln1_b     = (const float*)d_in[2];
  const float* in_proj_w = (const float*)d_in[3];
  const float* in_proj_b = (const float*)d_in[4];
  const float* out_proj_w= (const float*)d_in[5];
  const float* out_proj_b= (const float*)d_in[6];
  const float* ln2_w     = (const float*)d_in[7];
  const float* ln2_b     = (const float*)d_in[8];
  const float* Wg        = (const float*)d_in[9];
  const float* bg        = (const float*)d_in[10];
  const float* We        = (const float*)d_in[11];
  const float* be        = (const float*)d_in[12];
  const float* W1        = (const float*)d_in[13];
  const float* b1        = (const float*)d_in[14];
  const float* W2        = (const float*)d_in[15];
  const float* b2        = (const float*)d_in[16];
  float* out = (float*)d_out;

  char* ws = (char*)d_ws;
  size_t off = 0;
  auto alloc = [&](size_t bytes) -> char* {
    char* p = ws + off;
    off += (bytes + 255) & ~(size_t)255;
    return p;
  };
  u16*   inpTh = (u16*)  alloc((size_t)3 * D_ * D_ * 2);  // 3538944 B
  u16*   inpTl = (u16*)  alloc((size_t)3 * D_ * D_ * 2);  // contiguous -> 7077888 B region
  u16*   outpTh= (u16*)  alloc((size_t)D_ * D_ * 2);
  u16*   outpTl= (u16*)  alloc((size_t)D_ * D_ * 2);
  u16*   W1t  = (u16*)  alloc((size_t)E_ * HID_ * D_ * 2);
  u16*   W2t  = (u16*)  alloc((size_t)E_ * D_ * HID_ * 2);
  u16*   qkvh = (u16*)  alloc((size_t)NTOK * 3 * D_ * 2);
  u16*   qkvl = (u16*)  alloc((size_t)NTOK * 3 * D_ * 2);
  u16*   h1h  = (u16*)  alloc((size_t)NTOK * D_ * 2);     // 3145728 B
  u16*   h1l  = (u16*)  alloc((size_t)NTOK * D_ * 2);     // contiguous -> 6291456 B region
  u16*   vth  = (u16*)  alloc((size_t)B_ * NH_ * DH_ * S_ * 2);
  u16*   vtl  = (u16*)  alloc((size_t)B_ * NH_ * DH_ * S_ * 2);
  float* x2   = (float*)alloc((size_t)NTOK * D_ * 4);     // 6291456 B
  u16*   h2   = (u16*)  alloc((size_t)NTOK * D_ * 2);
  int*   flat = (int*)  alloc(NTOK * 4);
  float* pc   = (float*)alloc(NTOK * 4);
  int*   order= (int*)  alloc(NTOK * 4);
  int*   moeI = (int*)  alloc(32 * 4);
  // aliases (lifetimes disjoint):
  float* po0  = (float*)h1h;                       // 6291456 B over h1h+h1l (dead after QKV)
  float* po1  = (float*)inpTh;                     // 6291456 B over inpTh+inpTl (dead after QKV)
  float* po2  = x2;                                // x2 written only later by out-proj
  float* pmArr= (float*)((char*)inpTh + 6291456);  // 3*NGRP*64*4 = 294912 B
  float* plArr= (float*)((char*)inpTh + 6291456 + 294912);  // fits in 7077888 B region
  u16*   attnh= qkvh;
  u16*   attnl= qkvl;
  float* h2f  = (float*)qkvh;
  u16*   hid  = (u16*)qkvl;

  // fused weight prep
  k_prep<<<dim3(20736), dim3(256), 0, stream>>>(
      in_proj_w, out_proj_w, W1, W2, inpTh, inpTl, outpTh, outpTl, W1t, W2t);
  // LN1 (split output)
  k_layernorm<<<dim3(NTOK), dim3(256), 0, stream>>>(x, ln1_w, ln1_b, h1h, h1l, (float*)nullptr);
  // QKV (split GEMM, 128x64 tile; V columns transposed directly into vt)
  k_gemm3<0><<<dim3(NTOK / 128, 3 * D_ / 64), dim3(256), 0, stream>>>(
      h1h, h1l, inpTh, inpTl, in_proj_b, nullptr, qkvh, qkvl, nullptr, vth, vtl, NTOK, 3 * D_, D_);
  // attention split-K x3 partials (QBLK=128, LDS-staged)
  k_attn3<<<dim3(B_ * NH_, S_ / 128, KSPLIT), dim3(256), 0, stream>>>(
      qkvh, qkvl, vth, vtl, po0, po1, po2, pmArr, plArr);
  // merge thirds -> split bf16 attn (into qkv region)
  k_attn_merge<<<dim3(B_ * NH_, S_ / 64), dim3(256), 0, stream>>>(
      po0, po1, po2, pmArr, plArr, attnh, attnl);
  // out-proj + residual -> x2 (f32)
  k_gemm3<1><<<dim3(NTOK / 128, D_ / 64), dim3(256), 0, stream>>>(
      attnh, attnl, outpTh, outpTl, out_proj_b, x, nullptr, nullptr, x2,
      (u16*)nullptr, (u16*)nullptr, NTOK, D_, D_);
  // LN2: bf16 hi for MoE + f32 for router
  k_layernorm<<<dim3(NTOK), dim3(256), 0, stream>>>(x2, ln2_w, ln2_b, h2, (u16*)nullptr, h2f);
  // router + bucketing
  k_router<<<dim3(NTOK / 4), dim3(256), 0, stream>>>(h2f, Wg, bg, We, be, flat, pc);
  k_bucket<<<dim3(1), dim3(1024), 0, stream>>>(flat, moeI, order);
  // grouped expert GEMMs (e = blockIdx.x -> XCD pin)
  k_moe_gemm1<<<dim3(E_, NTOK / 64, HID_ / 64), dim3(256), 0, stream>>>(h2, W1t, b1, order, moeI, hid);
  k_moe_gemm2<<<dim3(E_, NTOK / 64, D_ / 64), dim3(256), 0, stream>>>(hid, W2t, b2, order, moeI, pc, x2, out);
}

// Round 12
// 209.341 us; speedup vs baseline: 1.0372x; 1.0372x over previous
//
#include <hip/hip_runtime.h>
#include <stdint.h>

#define B_ 2
#define S_ 1024
#define D_ 768
#define NH_ 12
#define DH_ 64
#define HID_ 1536
#define G_ 4
#define EPG_ 2
#define E_ 8
#define NTOK (B_*S_)
#define NGRP (B_*NH_*16)   // 384 (bh x qb64) groups
#define KSPLIT 3

typedef unsigned short u16;
typedef unsigned int u32;
typedef __bf16 bf16x8 __attribute__((ext_vector_type(8)));
typedef float f32x4 __attribute__((ext_vector_type(4)));
typedef u16 u16x4 __attribute__((ext_vector_type(4)));
typedef u16 u16x8 __attribute__((ext_vector_type(8)));
typedef u32 u32x4 __attribute__((ext_vector_type(4)));

struct BfPair { u16 hi, lo; };

__device__ __forceinline__ u16 f2bf(float f){
  unsigned u = __builtin_bit_cast(unsigned, f);
  u += 0x7FFFu + ((u >> 16) & 1u);
  return (u16)(u >> 16);
}
__device__ __forceinline__ float bf2f(u16 h){
  unsigned u = ((unsigned)h) << 16;
  return __builtin_bit_cast(float, u);
}
__device__ __forceinline__ BfPair split_bf(float v){
  BfPair p;
  p.hi = f2bf(v);
  p.lo = f2bf(v - bf2f(p.hi));
  return p;
}
__device__ __forceinline__ float gelu_tanh(float x){
  float t = 0.7978845608028654f * (x + 0.044715f * x * x * x);
  float e = __expf(2.f * t);
  float th = 1.f - 2.f / (e + 1.f);
  return 0.5f * x * (1.f + th);
}
__device__ __forceinline__ void gload_lds16(const void* g, void* l){
  __builtin_amdgcn_global_load_lds(
      (const __attribute__((address_space(1))) void*)g,
      (__attribute__((address_space(3))) void*)l, 16, 0, 0);
}

// ---------------- fused weight prep ----------------
__global__ __launch_bounds__(256) void k_prep(
    const float* __restrict__ in_proj_w, const float* __restrict__ out_proj_w,
    const float* __restrict__ W1, const float* __restrict__ W2,
    u16* __restrict__ inpTh, u16* __restrict__ inpTl,
    u16* __restrict__ outpTh, u16* __restrict__ outpTl,
    u16* __restrict__ W1t, u16* __restrict__ W2t){
  __shared__ float tile[32][33];
  int bid = blockIdx.x, t = threadIdx.x;
  if (bid < 2304){
    const float* src; u16 *dh, *dl; int i;
    if (bid < 1728){ src = in_proj_w; dh = inpTh; dl = inpTl; i = bid * 256 + t; }
    else           { src = out_proj_w; dh = outpTh; dl = outpTl; i = (bid - 1728) * 256 + t; }
    float4 v = ((const float4*)src)[i];
    u16x4 oh, ol;
    BfPair p0 = split_bf(v.x), p1 = split_bf(v.y), p2 = split_bf(v.z), p3 = split_bf(v.w);
    oh.x = p0.hi; ol.x = p0.lo; oh.y = p1.hi; ol.y = p1.lo;
    oh.z = p2.hi; ol.z = p2.lo; oh.w = p3.hi; ol.w = p3.lo;
    ((u16x4*)dh)[i] = oh;
    ((u16x4*)dl)[i] = ol;
  } else {
    const float* src; u16* dst; int R, C, cx, cy, e;
    if (bid < 11520){
      int r = bid - 2304; e = r / 1152; r %= 1152;
      R = D_; C = HID_; cx = r % 48; cy = r / 48;
      src = W1; dst = W1t;
    } else {
      int r = bid - 11520; e = r / 1152; r %= 1152;
      R = HID_; C = D_; cx = r % 24; cy = r / 24;
      src = W2; dst = W2t;
    }
    const float* s = src + (size_t)e * R * C;
    u16* d = dst + (size_t)e * R * C;
    int c0 = cx * 32, r0 = cy * 32;
    int tx = t & 31, ty = t >> 5;
    #pragma unroll
    for (int i = 0; i < 32; i += 8)
      tile[ty + i][tx] = s[(size_t)(r0 + ty + i) * C + c0 + tx];
    __syncthreads();
    #pragma unroll
    for (int i = 0; i < 32; i += 8)
      d[(size_t)(c0 + ty + i) * R + r0 + tx] = f2bf(tile[tx][ty + i]);
  }
}

// ---------------- layernorm ----------------
__global__ __launch_bounds__(256) void k_layernorm(
    const float* __restrict__ x, const float* __restrict__ w, const float* __restrict__ b,
    u16* __restrict__ oh, u16* __restrict__ ol, float* __restrict__ of){
  int row = blockIdx.x;
  const float* xr = x + (size_t)row * D_;
  int t = threadIdx.x;
  float v0 = xr[t], v1 = xr[t + 256], v2 = xr[t + 512];
  float s = v0 + v1 + v2;
  float sq = v0 * v0 + v1 * v1 + v2 * v2;
  #pragma unroll
  for (int m = 1; m < 64; m <<= 1){ s += __shfl_xor(s, m); sq += __shfl_xor(sq, m); }
  __shared__ float ls[4], lq[4];
  int wid = t >> 6;
  if ((t & 63) == 0){ ls[wid] = s; lq[wid] = sq; }
  __syncthreads();
  s = ls[0] + ls[1] + ls[2] + ls[3];
  sq = lq[0] + lq[1] + lq[2] + lq[3];
  float mean = s * (1.f / D_);
  float var = sq * (1.f / D_) - mean * mean;
  float rstd = rsqrtf(var + 1e-5f);
  #pragma unroll
  for (int i = 0; i < 3; i++){
    int dcol = t + i * 256;
    float v = (i == 0 ? v0 : (i == 1 ? v1 : v2));
    float y = (v - mean) * rstd * w[dcol] + b[dcol];
    BfPair p = split_bf(y);
    oh[(size_t)row * D_ + dcol] = p.hi;
    if (ol) ol[(size_t)row * D_ + dcol] = p.lo;
    if (of) of[(size_t)row * D_ + dcol] = y;
  }
}

// ------- pipelined split-precision GEMM 128xBN (BK=32, swizzled ^row&3) -------
// EPI 0 (BN=128): qkv mode — Q/K cols -> split bf16; V cols (2 heads/tile) -> vt.
// EPI 1 (BN=64): f32 + resid.
template<int EPI, int BN>
__global__ __launch_bounds__(256) void k_gemm3(
    const u16* __restrict__ Ah, const u16* __restrict__ Al,
    const u16* __restrict__ Bh, const u16* __restrict__ Bl,
    const float* __restrict__ bias, const float* __restrict__ resid,
    u16* __restrict__ outh, u16* __restrict__ outl, float* __restrict__ outf,
    u16* __restrict__ vth, u16* __restrict__ vtl,
    int M, int N, int K){
  constexpr int NWC = BN / 64;            // 2 (BN=128) or 1 (BN=64)
  constexpr int MI  = (NWC == 2) ? 4 : 2; // A-fragments per wave
  __shared__ alignas(16) u16 Ash[2][128 * 32];
  __shared__ alignas(16) u16 Asl[2][128 * 32];
  __shared__ alignas(16) u16 Bsh[2][BN * 32];
  __shared__ alignas(16) u16 Bsl[2][BN * 32];
  int m0 = blockIdx.x * 128, n0 = blockIdx.y * BN;
  int tid = threadIdx.x, w = tid >> 6, l = tid & 63;
  int wr = w / NWC, wc = w % NWC;
  f32x4 acc[MI][4];
  #pragma unroll
  for (int i = 0; i < MI; i++)
    #pragma unroll
    for (int j = 0; j < 4; j++) acc[i][j] = f32x4{0.f, 0.f, 0.f, 0.f};
  int srow = l >> 2;
  int scol = 8 * ((l & 3) ^ ((l >> 2) & 3));
  const u16* gAh0 = Ah + (size_t)(m0 + w * 32 + srow) * K + scol;
  const u16* gAh1 = gAh0 + (size_t)16 * K;
  const u16* gAl0 = Al + (size_t)(m0 + w * 32 + srow) * K + scol;
  const u16* gAl1 = gAl0 + (size_t)16 * K;
  int dA0 = (w * 32) * 32, dA1 = (w * 32 + 16) * 32;
  const u16 *gBh0, *gBh1, *gBl0, *gBl1;
  int dB0, dB1;
  if constexpr (NWC == 2){
    gBh0 = Bh + (size_t)(n0 + w * 32 + srow) * K + scol;
    gBh1 = gBh0 + (size_t)16 * K;
    gBl0 = Bl + (size_t)(n0 + w * 32 + srow) * K + scol;
    gBl1 = gBl0 + (size_t)16 * K;
    dB0 = (w * 32) * 32; dB1 = (w * 32 + 16) * 32;
  } else {
    gBh0 = Bh + (size_t)(n0 + w * 16 + srow) * K + scol;
    gBl0 = Bl + (size_t)(n0 + w * 16 + srow) * K + scol;
    gBh1 = gBh0; gBl1 = gBl0;
    dB0 = (w * 16) * 32; dB1 = dB0;
  }
  auto STAGE = [&](int buf, int k0){
    gload_lds16(gAh0 + k0, &Ash[buf][dA0]);
    gload_lds16(gAh1 + k0, &Ash[buf][dA1]);
    gload_lds16(gAl0 + k0, &Asl[buf][dA0]);
    gload_lds16(gAl1 + k0, &Asl[buf][dA1]);
    gload_lds16(gBh0 + k0, &Bsh[buf][dB0]);
    gload_lds16(gBl0 + k0, &Bsl[buf][dB0]);
    if constexpr (NWC == 2){
      gload_lds16(gBh1 + k0, &Bsh[buf][dB1]);
      gload_lds16(gBl1 + k0, &Bsl[buf][dB1]);
    }
  };
  STAGE(0, 0);
  __syncthreads();
  int nk = K / 32;
  int ca = (l >> 4) ^ (l & 3);
  for (int t = 0; t < nk; t++){
    int cur = t & 1;
    if (t + 1 < nk) STAGE(cur ^ 1, (t + 1) * 32);
    bf16x8 afh[MI], afl[MI], bfh[4], bfl[4];
    #pragma unroll
    for (int mi = 0; mi < MI; mi++){
      int ai = (wr * (MI * 16) + mi * 16 + (l & 15)) * 32 + 8 * ca;
      afh[mi] = *(const bf16x8*)&Ash[cur][ai];
      afl[mi] = *(const bf16x8*)&Asl[cur][ai];
    }
    #pragma unroll
    for (int ni = 0; ni < 4; ni++){
      int bi = (wc * 64 + ni * 16 + (l & 15)) * 32 + 8 * ca;
      bfh[ni] = *(const bf16x8*)&Bsh[cur][bi];
      bfl[ni] = *(const bf16x8*)&Bsl[cur][bi];
    }
    #pragma unroll
    for (int mi = 0; mi < MI; mi++)
      #pragma unroll
      for (int ni = 0; ni < 4; ni++){
        acc[mi][ni] = __builtin_amdgcn_mfma_f32_16x16x32_bf16(afh[mi], bfh[ni], acc[mi][ni], 0, 0, 0);
        acc[mi][ni] = __builtin_amdgcn_mfma_f32_16x16x32_bf16(afh[mi], bfl[ni], acc[mi][ni], 0, 0, 0);
        acc[mi][ni] = __builtin_amdgcn_mfma_f32_16x16x32_bf16(afl[mi], bfh[ni], acc[mi][ni], 0, 0, 0);
      }
    __syncthreads();
  }
  int r4 = (l >> 4) * 4, cc = l & 15;
  if constexpr (EPI == 0){
    if (n0 >= 2 * D_){
      // V columns: 128 tokens x 128 d-cols = 2 heads. Transpose via LDS halves.
      int hh0 = (n0 - 2 * D_) >> 6;   // even
      int bb = m0 >> 10;              // m0 / S_
      int sg0 = m0 & 1023;
      u16* Hh = (wc == 0) ? (u16*)&Ash[0][0] : (u16*)&Bsh[0][0];  // [64][128]
      u16* Hl = (wc == 0) ? (u16*)&Asl[0][0] : (u16*)&Bsl[0][0];
      #pragma unroll
      for (int mi = 0; mi < MI; mi++){
        #pragma unroll
        for (int ni = 0; ni < 4; ni++){
          int d = ni * 16 + cc;                      // within-half col
          float bv = bias ? bias[n0 + wc * 64 + d] : 0.f;
          int sl = wr * 64 + mi * 16 + r4;           // local token row
          u16x4 h4, l4;
          #pragma unroll
          for (int r = 0; r < 4; r++){
            BfPair p = split_bf(acc[mi][ni][r] + bv);
            h4[r] = p.hi; l4[r] = p.lo;
          }
          *(u16x4*)&Hh[d * 128 + sl] = h4;
          *(u16x4*)&Hl[d * 128 + sl] = l4;
        }
      }
      __syncthreads();
      for (int i = tid; i < 2048; i += 256){
        int half = i >> 10, idx = i & 1023;
        int d = idx >> 4, s8 = (idx & 15) * 8;
        const u16* sh = half ? (const u16*)&Bsh[0][0] : (const u16*)&Ash[0][0];
        const u16* slo = half ? (const u16*)&Bsl[0][0] : (const u16*)&Asl[0][0];
        size_t go = ((size_t)((bb * NH_ + hh0 + half) * DH_ + d)) * S_ + sg0 + s8;
        *(u16x8*)&vth[go] = *(const u16x8*)&sh[d * 128 + s8];
        *(u16x8*)&vtl[go] = *(const u16x8*)&slo[d * 128 + s8];
      }
      return;
    }
  }
  #pragma unroll
  for (int mi = 0; mi < MI; mi++){
    #pragma unroll
    for (int ni = 0; ni < 4; ni++){
      int col = n0 + wc * 64 + ni * 16 + cc;
      float bv = bias ? bias[col] : 0.f;
      #pragma unroll
      for (int r = 0; r < 4; r++){
        int row = m0 + wr * (MI * 16) + mi * 16 + r4 + r;
        float v = acc[mi][ni][r] + bv;
        if (EPI == 0){
          BfPair p = split_bf(v);
          outh[(size_t)row * N + col] = p.hi;
          outl[(size_t)row * N + col] = p.lo;
        } else {
          outf[(size_t)row * N + col] = v + resid[(size_t)row * N + col];
        }
      }
    }
  }
}

// ------- split-precision flash attention, split-K x3, KVBLK=32, swapped-QK in-reg softmax -------
// grid (bh=24, qb=16, ks=3)  [round-10 proven config]
__global__ __launch_bounds__(256) void k_attn3(
    const u16* __restrict__ qkvh, const u16* __restrict__ qkvl,
    const u16* __restrict__ vth, const u16* __restrict__ vtl,
    float* __restrict__ po0, float* __restrict__ po1, float* __restrict__ po2,
    float* __restrict__ pm, float* __restrict__ plsum){
  __shared__ alignas(16) u16 Ksh[2][32 * 64];
  __shared__ alignas(16) u16 Ksl[2][32 * 64];
  __shared__ alignas(16) u16 Vsh[2][64 * 32];
  __shared__ alignas(16) u16 Vsl[2][64 * 32];
  int bh = blockIdx.x, qb = blockIdx.y, ks = blockIdx.z;
  int b = bh / NH_, h = bh % NH_;
  int g = bh * 16 + qb;
  int tid = threadIdx.x, w = tid >> 6, l = tid & 63;
  int q0 = qb * 64 + w * 16;
  const int RS = 3 * D_;
  size_t qoff = (size_t)(b * S_ + q0 + (l & 15)) * RS + h * DH_ + 8 * (l >> 4);
  bf16x8 aqh[2], aql[2];
  aqh[0] = *(const bf16x8*)(qkvh + qoff); aqh[1] = *(const bf16x8*)(qkvh + qoff + 32);
  aql[0] = *(const bf16x8*)(qkvl + qoff); aql[1] = *(const bf16x8*)(qkvl + qoff + 32);
  f32x4 oacc[4];
  #pragma unroll
  for (int i = 0; i < 4; i++) oacc[i] = f32x4{0.f, 0.f, 0.f, 0.f};
  float mrun = -1e30f, lrun = 0.f;

  size_t koff = (size_t)(b * S_ + w * 8 + (l >> 3)) * RS + D_ + h * DH_ + 8 * ((l & 7) ^ (l >> 3));
  const u16* Kgh = qkvh + koff;
  const u16* Kgl = qkvl + koff;
  size_t voff = ((size_t)bh * DH_ + w * 16 + (l >> 2)) * S_ + 8 * ((l & 3) ^ ((l >> 2) & 3));
  const u16* Vgh = vth + voff;
  const u16* Vgl = vtl + voff;
  int wdst = w * 512;

  auto STAGE = [&](int buf, int akt){
    gload_lds16(Kgh + (size_t)(akt * 32) * RS, &Ksh[buf][wdst]);
    gload_lds16(Kgl + (size_t)(akt * 32) * RS, &Ksl[buf][wdst]);
    gload_lds16(Vgh + akt * 32, &Vsh[buf][wdst]);
    gload_lds16(Vgl + akt * 32, &Vsl[buf][wdst]);
  };
  int kt0 = (ks * 32) / KSPLIT;
  int ktE = ((ks + 1) * 32) / KSPLIT;
  STAGE(0, kt0);
  __syncthreads();

  int ck0 = (l >> 4) ^ (l & 7);
  int ck1 = ck0 ^ 4;
  int cv = (l >> 4) ^ (l & 3);
  int s1 = (l & 15) | ((l & 16) << 1);
  int s2 = s1 + 16;
  bool up = (l & 32) != 0;

  for (int kt = kt0; kt < ktE; kt++){
    int cur = (kt - kt0) & 1;
    if (kt + 1 < ktE) STAGE(cur ^ 1, kt + 1);
    f32x4 st[2];
    #pragma unroll
    for (int nt = 0; nt < 2; nt++){
      int rbase = (nt * 16 + (l & 15)) * 64;
      bf16x8 kh0 = *(const bf16x8*)&Ksh[cur][rbase + 8 * ck0];
      bf16x8 kh1 = *(const bf16x8*)&Ksh[cur][rbase + 8 * ck1];
      bf16x8 kl0 = *(const bf16x8*)&Ksl[cur][rbase + 8 * ck0];
      bf16x8 kl1 = *(const bf16x8*)&Ksl[cur][rbase + 8 * ck1];
      f32x4 c = f32x4{0.f, 0.f, 0.f, 0.f};
      c = __builtin_amdgcn_mfma_f32_16x16x32_bf16(kh0, aqh[0], c, 0, 0, 0);
      c = __builtin_amdgcn_mfma_f32_16x16x32_bf16(kh1, aqh[1], c, 0, 0, 0);
      c = __builtin_amdgcn_mfma_f32_16x16x32_bf16(kh0, aql[0], c, 0, 0, 0);
      c = __builtin_amdgcn_mfma_f32_16x16x32_bf16(kh1, aql[1], c, 0, 0, 0);
      c = __builtin_amdgcn_mfma_f32_16x16x32_bf16(kl0, aqh[0], c, 0, 0, 0);
      c = __builtin_amdgcn_mfma_f32_16x16x32_bf16(kl1, aqh[1], c, 0, 0, 0);
      st[nt] = c;
    }
    float mx = fmaxf(fmaxf(fmaxf(st[0][0], st[0][1]), fmaxf(st[0][2], st[0][3])),
                     fmaxf(fmaxf(st[1][0], st[1][1]), fmaxf(st[1][2], st[1][3])));
    mx = fmaxf(mx, __shfl_xor(mx, 16));
    mx = fmaxf(mx, __shfl_xor(mx, 32));
    mx *= 0.125f;
    if (!__all(mx <= mrun)){
      float mnew = fmaxf(mrun, mx);
      float alpha = __expf(mrun - mnew);
      lrun *= alpha;
      #pragma unroll
      for (int r = 0; r < 4; r++){
        float ar = __shfl(alpha, (l & 48) | (((l >> 4) << 2) + r));
        oacc[0][r] *= ar; oacc[1][r] *= ar; oacc[2][r] *= ar; oacc[3][r] *= ar;
      }
      mrun = mnew;
    }
    float p[8]; float sum = 0.f;
    #pragma unroll
    for (int j = 0; j < 8; j++){
      p[j] = __expf(st[j >> 2][j & 3] * 0.125f - mrun);
      sum += p[j];
    }
    sum += __shfl_xor(sum, 16);
    sum += __shfl_xor(sum, 32);
    lrun += sum;
    u32 pkh[4], pkl[4];
    #pragma unroll
    for (int i = 0; i < 4; i++){
      BfPair a = split_bf(p[2 * i]), bb = split_bf(p[2 * i + 1]);
      pkh[i] = (u32)a.hi | ((u32)bb.hi << 16);
      pkl[i] = (u32)a.lo | ((u32)bb.lo << 16);
    }
    u32 ah0 = __shfl((int)pkh[0], s1), ah1 = __shfl((int)pkh[1], s1);
    u32 ah2 = __shfl((int)pkh[2], s1), ah3 = __shfl((int)pkh[3], s1);
    u32 bh0 = __shfl((int)pkh[0], s2), bh1 = __shfl((int)pkh[1], s2);
    u32 bh2 = __shfl((int)pkh[2], s2), bh3 = __shfl((int)pkh[3], s2);
    u32 al0 = __shfl((int)pkl[0], s1), al1 = __shfl((int)pkl[1], s1);
    u32 al2 = __shfl((int)pkl[2], s1), al3 = __shfl((int)pkl[3], s1);
    u32 bl0 = __shfl((int)pkl[0], s2), bl1 = __shfl((int)pkl[1], s2);
    u32 bl2 = __shfl((int)pkl[2], s2), bl3 = __shfl((int)pkl[3], s2);
    u32x4 fh, fl;
    fh.x = up ? ah2 : ah0; fh.y = up ? ah3 : ah1; fh.z = up ? bh2 : bh0; fh.w = up ? bh3 : bh1;
    fl.x = up ? al2 : al0; fl.y = up ? al3 : al1; fl.z = up ? bl2 : bl0; fl.w = up ? bl3 : bl1;
    bf16x8 pa_h = __builtin_bit_cast(bf16x8, fh);
    bf16x8 pa_l = __builtin_bit_cast(bf16x8, fl);
    #pragma unroll
    for (int dt = 0; dt < 4; dt++){
      int vb = (dt * 16 + (l & 15)) * 32 + 8 * cv;
      bf16x8 bvh = *(const bf16x8*)&Vsh[cur][vb];
      bf16x8 bvl = *(const bf16x8*)&Vsl[cur][vb];
      oacc[dt] = __builtin_amdgcn_mfma_f32_16x16x32_bf16(pa_h, bvh, oacc[dt], 0, 0, 0);
      oacc[dt] = __builtin_amdgcn_mfma_f32_16x16x32_bf16(pa_h, bvl, oacc[dt], 0, 0, 0);
      oacc[dt] = __builtin_amdgcn_mfma_f32_16x16x32_bf16(pa_l, bvh, oacc[dt], 0, 0, 0);
    }
    __syncthreads();
  }
  float* po = (ks == 0) ? po0 : ((ks == 1) ? po1 : po2);
  #pragma unroll
  for (int dt = 0; dt < 4; dt++)
    #pragma unroll
    for (int r = 0; r < 4; r++){
      int qloc = w * 16 + (l >> 4) * 4 + r;
      int d = dt * 16 + (l & 15);
      po[((size_t)(g * 64 + qloc)) * 64 + d] = oacc[dt][r];
    }
  if (l < 16){
    pm[(ks * NGRP + g) * 64 + w * 16 + l] = mrun;
    plsum[(ks * NGRP + g) * 64 + w * 16 + l] = lrun;
  }
}

// ---------------- attn split-K merge (3-way) -> split bf16 attn output ----------------
__global__ __launch_bounds__(256) void k_attn_merge(
    const float* __restrict__ po0, const float* __restrict__ po1, const float* __restrict__ po2,
    const float* __restrict__ pm, const float* __restrict__ plsum,
    u16* __restrict__ oh, u16* __restrict__ ol){
  int bh = blockIdx.x, qb = blockIdx.y;
  int b = bh / NH_, h = bh % NH_;
  int g = bh * 16 + qb;
  int t = threadIdx.x;
  int q = t >> 2, d0 = (t & 3) * 16;
  float m0 = pm[g * 64 + q];
  float m1 = pm[(NGRP + g) * 64 + q];
  float m2 = pm[(2 * NGRP + g) * 64 + q];
  float l0 = plsum[g * 64 + q];
  float l1 = plsum[(NGRP + g) * 64 + q];
  float l2 = plsum[(2 * NGRP + g) * 64 + q];
  float M = fmaxf(fmaxf(m0, m1), m2);
  float a0 = __expf(m0 - M), a1 = __expf(m1 - M), a2 = __expf(m2 - M);
  float rcp = 1.f / (l0 * a0 + l1 * a1 + l2 * a2);
  size_t base = ((size_t)(g * 64 + q)) * 64 + d0;
  size_t orow = (size_t)(b * S_ + qb * 64 + q) * D_ + h * DH_ + d0;
  #pragma unroll
  for (int j = 0; j < 16; j++){
    float v = (po0[base + j] * a0 + po1[base + j] * a1 + po2[base + j] * a2) * rcp;
    BfPair p = split_bf(v);
    oh[orow + j] = p.hi;
    ol[orow + j] = p.lo;
  }
}

// ---------------- router (f32, no atomics) ----------------
__global__ __launch_bounds__(256) void k_router(
    const float* __restrict__ h2f, const float* __restrict__ Wg, const float* __restrict__ bg,
    const float* __restrict__ We, const float* __restrict__ be,
    int* __restrict__ flat, float* __restrict__ pc){
  int w = threadIdx.x >> 6, l = threadIdx.x & 63;
  int n = blockIdx.x * 4 + w;
  const float* hr = h2f + (size_t)n * D_;
  float pl[4] = {0.f, 0.f, 0.f, 0.f};
  for (int d = l; d < D_; d += 64){
    float hv = hr[d];
    float4 wg = *(const float4*)&Wg[d * 4];
    pl[0] += hv * wg.x; pl[1] += hv * wg.y; pl[2] += hv * wg.z; pl[3] += hv * wg.w;
  }
  #pragma unroll
  for (int m = 1; m < 64; m <<= 1)
    #pragma unroll
    for (int g = 0; g < 4; g++) pl[g] += __shfl_xor(pl[g], m);
  float lg[4];
  #pragma unroll
  for (int g = 0; g < 4; g++) lg[g] = pl[g] + bg[g];
  int gi = 0; float gm = lg[0];
  #pragma unroll
  for (int g = 1; g < 4; g++) if (lg[g] > gm){ gm = lg[g]; gi = g; }
  float gs = 0.f;
  #pragma unroll
  for (int g = 0; g < 4; g++) gs += expf(lg[g] - gm);
  float pg = 1.f / gs;
  float e0 = 0.f, e1 = 0.f;
  for (int d = l; d < D_; d += 64){
    float hv = hr[d];
    float2 we = *(const float2*)&We[((size_t)gi * D_ + d) * 2];
    e0 += hv * we.x; e1 += hv * we.y;
  }
  #pragma unroll
  for (int m = 1; m < 64; m <<= 1){ e0 += __shfl_xor(e0, m); e1 += __shfl_xor(e1, m); }
  e0 += be[gi * 2]; e1 += be[gi * 2 + 1];
  int ei; float pe;
  if (e1 > e0){ ei = 1; pe = 1.f / (1.f + expf(e0 - e1)); }
  else        { ei = 0; pe = 1.f / (1.f + expf(e1 - e0)); }
  if (l == 0){
    flat[n] = gi * 2 + ei;
    pc[n] = pg * pe;
  }
}

// ---------------- single-block bucketing ----------------
__global__ __launch_bounds__(1024) void k_bucket(
    const int* __restrict__ flat, int* __restrict__ moeI, int* __restrict__ order){
  __shared__ int cnt[E_], off[E_], cur[E_];
  int t = threadIdx.x;
  if (t < E_){ cnt[t] = 0; cur[t] = 0; }
  __syncthreads();
  int n0 = t, n1 = t + 1024;
  int f0 = flat[n0], f1 = flat[n1];
  atomicAdd(&cnt[f0], 1);
  atomicAdd(&cnt[f1], 1);
  __syncthreads();
  if (t == 0){
    int s = 0;
    for (int e = 0; e < E_; e++){
      off[e] = s; moeI[16 + e] = s; moeI[e] = cnt[e]; s += cnt[e];
    }
  }
  __syncthreads();
  int p0 = atomicAdd(&cur[f0], 1);
  order[off[f0] + p0] = n0;
  int p1 = atomicAdd(&cur[f1], 1);
  order[off[f1] + p1] = n1;
}

// ------- pipelined grouped GEMM 1 (64x64, BK=64, swizzled ^row&7) -------
__global__ __launch_bounds__(256) void k_moe_gemm1(
    const u16* __restrict__ h2, const u16* __restrict__ W1t, const float* __restrict__ b1,
    const int* __restrict__ order, const int* __restrict__ moeI, u16* __restrict__ hid){
  int e = blockIdx.x, mt = blockIdx.y, nt = blockIdx.z;
  int cnt = moeI[e];
  if (mt * 64 >= cnt) return;
  int off = moeI[16 + e];
  __shared__ alignas(16) u16 As[2][64 * 64];
  __shared__ alignas(16) u16 Bs[2][64 * 64];
  int tid = threadIdx.x, w = tid >> 6, l = tid & 63;
  int wr = w >> 1, wc = w & 1;
  f32x4 acc[2][2];
  #pragma unroll
  for (int i = 0; i < 2; i++)
    #pragma unroll
    for (int j = 0; j < 2; j++) acc[i][j] = f32x4{0.f, 0.f, 0.f, 0.f};
  int r0 = w * 16 + (l >> 3);
  int sch = 8 * ((l & 7) ^ (l >> 3));
  int tokA0 = order[off + min(mt * 64 + r0, cnt - 1)];
  int tokA1 = order[off + min(mt * 64 + r0 + 8, cnt - 1)];
  const u16* gA0 = h2 + (size_t)tokA0 * D_ + sch;
  const u16* gA1 = h2 + (size_t)tokA1 * D_ + sch;
  const u16* gB0 = W1t + (size_t)e * HID_ * D_ + (size_t)(nt * 64 + r0) * D_ + sch;
  const u16* gB1 = gB0 + (size_t)8 * D_;
  int d0 = (w * 16) * 64, d1 = (w * 16 + 8) * 64;
  auto STAGE = [&](int buf, int k0){
    gload_lds16(gA0 + k0, &As[buf][d0]);
    gload_lds16(gA1 + k0, &As[buf][d1]);
    gload_lds16(gB0 + k0, &Bs[buf][d0]);
    gload_lds16(gB1 + k0, &Bs[buf][d1]);
  };
  STAGE(0, 0);
  __syncthreads();
  int c0 = (l >> 4) ^ (l & 7);
  int c1 = ((l >> 4) + 4) ^ (l & 7);
  const int nk = D_ / 64;
  for (int t = 0; t < nk; t++){
    int cur = t & 1;
    if (t + 1 < nk) STAGE(cur ^ 1, (t + 1) * 64);
    bf16x8 af[2][2], bfr[2][2];
    #pragma unroll
    for (int mi = 0; mi < 2; mi++){
      int rbase = (wr * 32 + mi * 16 + (l & 15)) * 64;
      af[mi][0] = *(const bf16x8*)&As[cur][rbase + 8 * c0];
      af[mi][1] = *(const bf16x8*)&As[cur][rbase + 8 * c1];
    }
    #pragma unroll
    for (int ni = 0; ni < 2; ni++){
      int rbase = (wc * 32 + ni * 16 + (l & 15)) * 64;
      bfr[ni][0] = *(const bf16x8*)&Bs[cur][rbase + 8 * c0];
      bfr[ni][1] = *(const bf16x8*)&Bs[cur][rbase + 8 * c1];
    }
    #pragma unroll
    for (int mi = 0; mi < 2; mi++)
      #pragma unroll
      for (int ni = 0; ni < 2; ni++){
        acc[mi][ni] = __builtin_amdgcn_mfma_f32_16x16x32_bf16(af[mi][0], bfr[ni][0], acc[mi][ni], 0, 0, 0);
        acc[mi][ni] = __builtin_amdgcn_mfma_f32_16x16x32_bf16(af[mi][1], bfr[ni][1], acc[mi][ni], 0, 0, 0);
      }
    __syncthreads();
  }
  int r4 = (l >> 4) * 4, cc = l & 15;
  #pragma unroll
  for (int mi = 0; mi < 2; mi++){
    #pragma unroll
    for (int ni = 0; ni < 2; ni++){
      int col = nt * 64 + wc * 32 + ni * 16 + cc;
      float bv = b1[e * HID_ + col];
      #pragma unroll
      for (int r = 0; r < 4; r++){
        int rowl = mt * 64 + wr * 32 + mi * 16 + r4 + r;
        if (rowl < cnt){
          float v = gelu_tanh(acc[mi][ni][r] + bv);
          hid[(size_t)(off + rowl) * HID_ + col] = f2bf(v);
        }
      }
    }
  }
}

// ------- pipelined grouped GEMM 2 (64x64, BK=64, swizzled) -------
__global__ __launch_bounds__(256) void k_moe_gemm2(
    const u16* __restrict__ hid, const u16* __restrict__ W2t, const float* __restrict__ b2,
    const int* __restrict__ order, const int* __restrict__ moeI,
    const float* __restrict__ pc, const float* __restrict__ x2, float* __restrict__ out){
  int e = blockIdx.x, mt = blockIdx.y, nt = blockIdx.z;
  int cnt = moeI[e];
  if (mt * 64 >= cnt) return;
  int off = moeI[16 + e];
  __shared__ alignas(16) u16 As[2][64 * 64];
  __shared__ alignas(16) u16 Bs[2][64 * 64];
  int tid = threadIdx.x, w = tid >> 6, l = tid & 63;
  int wr = w >> 1, wc = w & 1;
  f32x4 acc[2][2];
  #pragma unroll
  for (int i = 0; i < 2; i++)
    #pragma unroll
    for (int j = 0; j < 2; j++) acc[i][j] = f32x4{0.f, 0.f, 0.f, 0.f};
  int r0 = w * 16 + (l >> 3);
  int sch = 8 * ((l & 7) ^ (l >> 3));
  int ar0 = off + min(mt * 64 + r0, cnt - 1);
  int ar1 = off + min(mt * 64 + r0 + 8, cnt - 1);
  const u16* gA0 = hid + (size_t)ar0 * HID_ + sch;
  const u16* gA1 = hid + (size_t)ar1 * HID_ + sch;
  const u16* gB0 = W2t + (size_t)e * D_ * HID_ + (size_t)(nt * 64 + r0) * HID_ + sch;
  const u16* gB1 = gB0 + (size_t)8 * HID_;
  int d0 = (w * 16) * 64, d1 = (w * 16 + 8) * 64;
  auto STAGE = [&](int buf, int k0){
    gload_lds16(gA0 + k0, &As[buf][d0]);
    gload_lds16(gA1 + k0, &As[buf][d1]);
    gload_lds16(gB0 + k0, &Bs[buf][d0]);
    gload_lds16(gB1 + k0, &Bs[buf][d1]);
  };
  STAGE(0, 0);
  __syncthreads();
  int c0 = (l >> 4) ^ (l & 7);
  int c1 = ((l >> 4) + 4) ^ (l & 7);
  const int nk = HID_ / 64;
  for (int t = 0; t < nk; t++){
    int cur = t & 1;
    if (t + 1 < nk) STAGE(cur ^ 1, (t + 1) * 64);
    bf16x8 af[2][2], bfr[2][2];
    #pragma unroll
    for (int mi = 0; mi < 2; mi++){
      int rbase = (wr * 32 + mi * 16 + (l & 15)) * 64;
      af[mi][0] = *(const bf16x8*)&As[cur][rbase + 8 * c0];
      af[mi][1] = *(const bf16x8*)&As[cur][rbase + 8 * c1];
    }
    #pragma unroll
    for (int ni = 0; ni < 2; ni++){
      int rbase = (wc * 32 + ni * 16 + (l & 15)) * 64;
      bfr[ni][0] = *(const bf16x8*)&Bs[cur][rbase + 8 * c0];
      bfr[ni][1] = *(const bf16x8*)&Bs[cur][rbase + 8 * c1];
    }
    #pragma unroll
    for (int mi = 0; mi < 2; mi++)
      #pragma unroll
      for (int ni = 0; ni < 2; ni++){
        acc[mi][ni] = __builtin_amdgcn_mfma_f32_16x16x32_bf16(af[mi][0], bfr[ni][0], acc[mi][ni], 0, 0, 0);
        acc[mi][ni] = __builtin_amdgcn_mfma_f32_16x16x32_bf16(af[mi][1], bfr[ni][1], acc[mi][ni], 0, 0, 0);
      }
    __syncthreads();
  }
  int r4 = (l >> 4) * 4, cc = l & 15;
  #pragma unroll
  for (int mi = 0; mi < 2; mi++){
    #pragma unroll
    for (int r = 0; r < 4; r++){
      int rowl = mt * 64 + wr * 32 + mi * 16 + r4 + r;
      if (rowl < cnt){
        int tok = order[off + rowl];
        float pv = pc[tok];
        #pragma unroll
        for (int ni = 0; ni < 2; ni++){
          int col = nt * 64 + wc * 32 + ni * 16 + cc;
          float v = acc[mi][ni][r] + b2[e * D_ + col];
          out[(size_t)tok * D_ + col] = x2[(size_t)tok * D_ + col] + pv * v;
        }
      }
    }
  }
}

extern "C" void kernel_launch(void* const* d_in, const int* in_sizes, int n_in,
                              void* d_out, int out_size, void* d_ws, size_t ws_size,
                              hipStream_t stream){
  const float* x         = (const float*)d_in[0];
  const float* ln1_w     = (const float*)d_in[1];
  const float* ln1_b     = (const float*)d_in[2];
  const float* in_proj_w = (const float*)d_in[3];
  const float* in_proj_b = (const float*)d_in[4];
  const float* out_proj_w= (const float*)d_in[5];
  const float* out_proj_b= (const float*)d_in[6];
  const float* ln2_w     = (const float*)d_in[7];
  const float* ln2_b     = (const float*)d_in[8];
  const float* Wg        = (const float*)d_in[9];
  const float* bg        = (const float*)d_in[10];
  const float* We        = (const float*)d_in[11];
  const float* be        = (const float*)d_in[12];
  const float* W1        = (const float*)d_in[13];
  const float* b1        = (const float*)d_in[14];
  const float* W2        = (const float*)d_in[15];
  const float* b2        = (const float*)d_in[16];
  float* out = (float*)d_out;

  char* ws = (char*)d_ws;
  size_t off = 0;
  auto alloc = [&](size_t bytes) -> char* {
    char* p = ws + off;
    off += (bytes + 255) & ~(size_t)255;
    return p;
  };
  u16*   inpTh = (u16*)  alloc((size_t)3 * D_ * D_ * 2);
  u16*   inpTl = (u16*)  alloc((size_t)3 * D_ * D_ * 2);
  u16*   outpTh= (u16*)  alloc((size_t)D_ * D_ * 2);
  u16*   outpTl= (u16*)  alloc((size_t)D_ * D_ * 2);
  u16*   W1t  = (u16*)  alloc((size_t)E_ * HID_ * D_ * 2);
  u16*   W2t  = (u16*)  alloc((size_t)E_ * D_ * HID_ * 2);
  u16*   qkvh = (u16*)  alloc((size_t)NTOK * 3 * D_ * 2);
  u16*   qkvl = (u16*)  alloc((size_t)NTOK * 3 * D_ * 2);
  u16*   h1h  = (u16*)  alloc((size_t)NTOK * D_ * 2);
  u16*   h1l  = (u16*)  alloc((size_t)NTOK * D_ * 2);
  u16*   vth  = (u16*)  alloc((size_t)B_ * NH_ * DH_ * S_ * 2);
  u16*   vtl  = (u16*)  alloc((size_t)B_ * NH_ * DH_ * S_ * 2);
  float* x2   = (float*)alloc((size_t)NTOK * D_ * 4);
  u16*   h2   = (u16*)  alloc((size_t)NTOK * D_ * 2);
  int*   flat = (int*)  alloc(NTOK * 4);
  float* pc   = (float*)alloc(NTOK * 4);
  int*   order= (int*)  alloc(NTOK * 4);
  int*   moeI = (int*)  alloc(32 * 4);
  // aliases (lifetimes disjoint):
  float* po0  = (float*)h1h;                       // over h1h+h1l (dead after QKV)
  float* po1  = (float*)inpTh;                     // over inpTh+inpTl (dead after QKV)
  float* po2  = x2;                                // x2 written only later by out-proj
  float* pmArr= (float*)((char*)inpTh + 6291456);
  float* plArr= (float*)((char*)inpTh + 6291456 + 294912);
  u16*   attnh= qkvh;
  u16*   attnl= qkvl;
  float* h2f  = (float*)qkvh;
  u16*   hid  = (u16*)qkvl;

  // fused weight prep
  k_prep<<<dim3(20736), dim3(256), 0, stream>>>(
      in_proj_w, out_proj_w, W1, W2, inpTh, inpTl, outpTh, outpTl, W1t, W2t);
  // LN1 (split output)
  k_layernorm<<<dim3(NTOK), dim3(256), 0, stream>>>(x, ln1_w, ln1_b, h1h, h1l, (float*)nullptr);
  // QKV (split GEMM, 128x128 tile; V columns transposed directly into vt)
  k_gemm3<0, 128><<<dim3(NTOK / 128, 3 * D_ / 128), dim3(256), 0, stream>>>(
      h1h, h1l, inpTh, inpTl, in_proj_b, nullptr, qkvh, qkvl, nullptr, vth, vtl, NTOK, 3 * D_, D_);
  // attention split-K x3 partials (QBLK=64, LDS-staged)
  k_attn3<<<dim3(B_ * NH_, S_ / 64, KSPLIT), dim3(256), 0, stream>>>(
      qkvh, qkvl, vth, vtl, po0, po1, po2, pmArr, plArr);
  // merge thirds -> split bf16 attn (into qkv region)
  k_attn_merge<<<dim3(B_ * NH_, S_ / 64), dim3(256), 0, stream>>>(
      po0, po1, po2, pmArr, plArr, attnh, attnl);
  // out-proj + residual -> x2 (f32), 128x64 tile
  k_gemm3<1, 64><<<dim3(NTOK / 128, D_ / 64), dim3(256), 0, stream>>>(
      attnh, attnl, outpTh, outpTl, out_proj_b, x, nullptr, nullptr, x2,
      (u16*)nullptr, (u16*)nullptr, NTOK, D_, D_);
  // LN2: bf16 hi for MoE + f32 for router
  k_layernorm<<<dim3(NTOK), dim3(256), 0, stream>>>(x2, ln2_w, ln2_b, h2, (u16*)nullptr, h2f);
  // router + bucketing
  k_router<<<dim3(NTOK / 4), dim3(256), 0, stream>>>(h2f, Wg, bg, We, be, flat, pc);
  k_bucket<<<dim3(1), dim3(1024), 0, stream>>>(flat, moeI, order);
  // grouped expert GEMMs (e = blockIdx.x -> XCD pin)
  k_moe_gemm1<<<dim3(E_, NTOK / 64, HID_ / 64), dim3(256), 0, stream>>>(h2, W1t, b1, order, moeI, hid);
  k_moe_gemm2<<<dim3(E_, NTOK / 64, D_ / 64), dim3(256), 0, stream>>>(hid, W2t, b2, order, moeI, pc, x2, out);
}

// Round 13
// 199.895 us; speedup vs baseline: 1.0863x; 1.0473x over previous
//
#include <hip/hip_runtime.h>
#include <stdint.h>

#define B_ 2
#define S_ 1024
#define D_ 768
#define NH_ 12
#define DH_ 64
#define HID_ 1536
#define G_ 4
#define EPG_ 2
#define E_ 8
#define NTOK (B_*S_)
#define NGRP (B_*NH_*16)   // 384 (bh x qb64) groups
#define KSPLIT 3

typedef unsigned short u16;
typedef unsigned int u32;
typedef __bf16 bf16x8 __attribute__((ext_vector_type(8)));
typedef float f32x4 __attribute__((ext_vector_type(4)));
typedef u16 u16x4 __attribute__((ext_vector_type(4)));
typedef u16 u16x8 __attribute__((ext_vector_type(8)));
typedef u32 u32x4 __attribute__((ext_vector_type(4)));

struct BfPair { u16 hi, lo; };

__device__ __forceinline__ u16 f2bf(float f){
  unsigned u = __builtin_bit_cast(unsigned, f);
  u += 0x7FFFu + ((u >> 16) & 1u);
  return (u16)(u >> 16);
}
__device__ __forceinline__ float bf2f(u16 h){
  unsigned u = ((unsigned)h) << 16;
  return __builtin_bit_cast(float, u);
}
__device__ __forceinline__ BfPair split_bf(float v){
  BfPair p;
  p.hi = f2bf(v);
  p.lo = f2bf(v - bf2f(p.hi));
  return p;
}
__device__ __forceinline__ float gelu_tanh(float x){
  float t = 0.7978845608028654f * (x + 0.044715f * x * x * x);
  float e = __expf(2.f * t);
  float th = 1.f - 2.f / (e + 1.f);
  return 0.5f * x * (1.f + th);
}
__device__ __forceinline__ void gload_lds16(const void* g, void* l){
  __builtin_amdgcn_global_load_lds(
      (const __attribute__((address_space(1))) void*)g,
      (__attribute__((address_space(3))) void*)l, 16, 0, 0);
}

// ---------------- fused weight prep ----------------
__global__ __launch_bounds__(256) void k_prep(
    const float* __restrict__ in_proj_w, const float* __restrict__ out_proj_w,
    const float* __restrict__ W1, const float* __restrict__ W2,
    u16* __restrict__ inpTh, u16* __restrict__ inpTl,
    u16* __restrict__ outpTh, u16* __restrict__ outpTl,
    u16* __restrict__ W1t, u16* __restrict__ W2t){
  __shared__ float tile[32][33];
  int bid = blockIdx.x, t = threadIdx.x;
  if (bid < 2304){
    const float* src; u16 *dh, *dl; int i;
    if (bid < 1728){ src = in_proj_w; dh = inpTh; dl = inpTl; i = bid * 256 + t; }
    else           { src = out_proj_w; dh = outpTh; dl = outpTl; i = (bid - 1728) * 256 + t; }
    float4 v = ((const float4*)src)[i];
    u16x4 oh, ol;
    BfPair p0 = split_bf(v.x), p1 = split_bf(v.y), p2 = split_bf(v.z), p3 = split_bf(v.w);
    oh.x = p0.hi; ol.x = p0.lo; oh.y = p1.hi; ol.y = p1.lo;
    oh.z = p2.hi; ol.z = p2.lo; oh.w = p3.hi; ol.w = p3.lo;
    ((u16x4*)dh)[i] = oh;
    ((u16x4*)dl)[i] = ol;
  } else {
    const float* src; u16* dst; int R, C, cx, cy, e;
    if (bid < 11520){
      int r = bid - 2304; e = r / 1152; r %= 1152;
      R = D_; C = HID_; cx = r % 48; cy = r / 48;
      src = W1; dst = W1t;
    } else {
      int r = bid - 11520; e = r / 1152; r %= 1152;
      R = HID_; C = D_; cx = r % 24; cy = r / 24;
      src = W2; dst = W2t;
    }
    const float* s = src + (size_t)e * R * C;
    u16* d = dst + (size_t)e * R * C;
    int c0 = cx * 32, r0 = cy * 32;
    int tx = t & 31, ty = t >> 5;
    #pragma unroll
    for (int i = 0; i < 32; i += 8)
      tile[ty + i][tx] = s[(size_t)(r0 + ty + i) * C + c0 + tx];
    __syncthreads();
    #pragma unroll
    for (int i = 0; i < 32; i += 8)
      d[(size_t)(c0 + ty + i) * R + r0 + tx] = f2bf(tile[tx][ty + i]);
  }
}

// ---------------- layernorm (ROUTE=1: fused MoE router) ----------------
template<int ROUTE>
__global__ __launch_bounds__(256) void k_layernorm(
    const float* __restrict__ x, const float* __restrict__ w, const float* __restrict__ b,
    u16* __restrict__ oh, u16* __restrict__ ol,
    const float* __restrict__ Wg, const float* __restrict__ bg,
    const float* __restrict__ We, const float* __restrict__ be,
    int* __restrict__ flat, float* __restrict__ pc){
  int row = blockIdx.x;
  const float* xr = x + (size_t)row * D_;
  int t = threadIdx.x;
  float v0 = xr[t], v1 = xr[t + 256], v2 = xr[t + 512];
  float s = v0 + v1 + v2;
  float sq = v0 * v0 + v1 * v1 + v2 * v2;
  #pragma unroll
  for (int m = 1; m < 64; m <<= 1){ s += __shfl_xor(s, m); sq += __shfl_xor(sq, m); }
  __shared__ float ls[4], lq[4];
  __shared__ float lred[4][4];
  int wid = t >> 6;
  if ((t & 63) == 0){ ls[wid] = s; lq[wid] = sq; }
  __syncthreads();
  s = ls[0] + ls[1] + ls[2] + ls[3];
  sq = lq[0] + lq[1] + lq[2] + lq[3];
  float mean = s * (1.f / D_);
  float var = sq * (1.f / D_) - mean * mean;
  float rstd = rsqrtf(var + 1e-5f);
  float y0, y1, y2;
  #pragma unroll
  for (int i = 0; i < 3; i++){
    int dcol = t + i * 256;
    float v = (i == 0 ? v0 : (i == 1 ? v1 : v2));
    float y = (v - mean) * rstd * w[dcol] + b[dcol];
    if (i == 0) y0 = y; else if (i == 1) y1 = y; else y2 = y;
    BfPair p = split_bf(y);
    oh[(size_t)row * D_ + dcol] = p.hi;
    if (ROUTE == 0) ol[(size_t)row * D_ + dcol] = p.lo;
  }
  if (ROUTE == 1){
    // group logits: gp[j] = sum_d y[d]*Wg[d][j]
    float gp[4] = {0.f, 0.f, 0.f, 0.f};
    #pragma unroll
    for (int i = 0; i < 3; i++){
      int dcol = t + i * 256;
      float y = (i == 0 ? y0 : (i == 1 ? y1 : y2));
      float4 wg = *(const float4*)&Wg[dcol * 4];
      gp[0] += y * wg.x; gp[1] += y * wg.y; gp[2] += y * wg.z; gp[3] += y * wg.w;
    }
    #pragma unroll
    for (int m = 1; m < 64; m <<= 1)
      #pragma unroll
      for (int j = 0; j < 4; j++) gp[j] += __shfl_xor(gp[j], m);
    if ((t & 63) == 0)
      #pragma unroll
      for (int j = 0; j < 4; j++) lred[wid][j] = gp[j];
    __syncthreads();
    float lg[4];
    #pragma unroll
    for (int j = 0; j < 4; j++)
      lg[j] = lred[0][j] + lred[1][j] + lred[2][j] + lred[3][j] + bg[j];
    int gi = 0; float gm = lg[0];
    #pragma unroll
    for (int j = 1; j < 4; j++) if (lg[j] > gm){ gm = lg[j]; gi = j; }
    float gs = 0.f;
    #pragma unroll
    for (int j = 0; j < 4; j++) gs += expf(lg[j] - gm);
    float pg = 1.f / gs;
    // expert logits within group gi
    float e0 = 0.f, e1 = 0.f;
    #pragma unroll
    for (int i = 0; i < 3; i++){
      int dcol = t + i * 256;
      float y = (i == 0 ? y0 : (i == 1 ? y1 : y2));
      float2 we = *(const float2*)&We[((size_t)gi * D_ + dcol) * 2];
      e0 += y * we.x; e1 += y * we.y;
    }
    #pragma unroll
    for (int m = 1; m < 64; m <<= 1){ e0 += __shfl_xor(e0, m); e1 += __shfl_xor(e1, m); }
    __syncthreads();
    if ((t & 63) == 0){ lred[wid][0] = e0; lred[wid][1] = e1; }
    __syncthreads();
    if (t == 0){
      float E0 = lred[0][0] + lred[1][0] + lred[2][0] + lred[3][0] + be[gi * 2];
      float E1 = lred[0][1] + lred[1][1] + lred[2][1] + lred[3][1] + be[gi * 2 + 1];
      int ei; float pe;
      if (E1 > E0){ ei = 1; pe = 1.f / (1.f + expf(E0 - E1)); }
      else        { ei = 0; pe = 1.f / (1.f + expf(E1 - E0)); }
      flat[row] = gi * 2 + ei;
      pc[row] = pg * pe;
    }
  }
}

// ------- pipelined split-precision GEMM 128x64 (BK=32, swizzled ^row&3) -------
// EPI 0: qkv mode — Q/K cols -> split bf16; V cols -> transposed into vth/vtl.
// EPI 1: f32 + resid.
template<int EPI>
__global__ __launch_bounds__(256) void k_gemm3(
    const u16* __restrict__ Ah, const u16* __restrict__ Al,
    const u16* __restrict__ Bh, const u16* __restrict__ Bl,
    const float* __restrict__ bias, const float* __restrict__ resid,
    u16* __restrict__ outh, u16* __restrict__ outl, float* __restrict__ outf,
    u16* __restrict__ vth, u16* __restrict__ vtl,
    int M, int N, int K){
  __shared__ alignas(16) u16 Ash[2][128 * 32];
  __shared__ alignas(16) u16 Asl[2][128 * 32];
  __shared__ alignas(16) u16 Bsh[2][64 * 32];
  __shared__ alignas(16) u16 Bsl[2][64 * 32];
  int m0 = blockIdx.x * 128, n0 = blockIdx.y * 64;
  int tid = threadIdx.x, w = tid >> 6, l = tid & 63;
  f32x4 acc[2][4];
  #pragma unroll
  for (int i = 0; i < 2; i++)
    #pragma unroll
    for (int j = 0; j < 4; j++) acc[i][j] = f32x4{0.f, 0.f, 0.f, 0.f};
  int srow = l >> 2;
  int scol = 8 * ((l & 3) ^ ((l >> 2) & 3));
  const u16* gAh0 = Ah + (size_t)(m0 + w * 32 + srow) * K + scol;
  const u16* gAh1 = gAh0 + (size_t)16 * K;
  const u16* gAl0 = Al + (size_t)(m0 + w * 32 + srow) * K + scol;
  const u16* gAl1 = gAl0 + (size_t)16 * K;
  const u16* gBh = Bh + (size_t)(n0 + w * 16 + srow) * K + scol;
  const u16* gBl = Bl + (size_t)(n0 + w * 16 + srow) * K + scol;
  int dA0 = (w * 32) * 32, dA1 = (w * 32 + 16) * 32, dB = (w * 16) * 32;
  auto STAGE = [&](int buf, int k0){
    gload_lds16(gAh0 + k0, &Ash[buf][dA0]);
    gload_lds16(gAh1 + k0, &Ash[buf][dA1]);
    gload_lds16(gAl0 + k0, &Asl[buf][dA0]);
    gload_lds16(gAl1 + k0, &Asl[buf][dA1]);
    gload_lds16(gBh + k0, &Bsh[buf][dB]);
    gload_lds16(gBl + k0, &Bsl[buf][dB]);
  };
  STAGE(0, 0);
  __syncthreads();
  int nk = K / 32;
  int ca = (l >> 4) ^ (l & 3);
  int ai0 = (w * 32 + (l & 15)) * 32 + 8 * ca;
  int ai1 = ai0 + 16 * 32;
  for (int t = 0; t < nk; t++){
    int cur = t & 1;
    if (t + 1 < nk) STAGE(cur ^ 1, (t + 1) * 32);
    bf16x8 afh[2], afl[2], bfh[4], bfl[4];
    afh[0] = *(const bf16x8*)&Ash[cur][ai0];
    afh[1] = *(const bf16x8*)&Ash[cur][ai1];
    afl[0] = *(const bf16x8*)&Asl[cur][ai0];
    afl[1] = *(const bf16x8*)&Asl[cur][ai1];
    #pragma unroll
    for (int ni = 0; ni < 4; ni++){
      int bi = (ni * 16 + (l & 15)) * 32 + 8 * ca;
      bfh[ni] = *(const bf16x8*)&Bsh[cur][bi];
      bfl[ni] = *(const bf16x8*)&Bsl[cur][bi];
    }
    #pragma unroll
    for (int mi = 0; mi < 2; mi++)
      #pragma unroll
      for (int ni = 0; ni < 4; ni++){
        acc[mi][ni] = __builtin_amdgcn_mfma_f32_16x16x32_bf16(afh[mi], bfh[ni], acc[mi][ni], 0, 0, 0);
        acc[mi][ni] = __builtin_amdgcn_mfma_f32_16x16x32_bf16(afh[mi], bfl[ni], acc[mi][ni], 0, 0, 0);
        acc[mi][ni] = __builtin_amdgcn_mfma_f32_16x16x32_bf16(afl[mi], bfh[ni], acc[mi][ni], 0, 0, 0);
      }
    __syncthreads();
  }
  int r4 = (l >> 4) * 4, cc = l & 15;
  if (EPI == 0 && n0 >= 2 * D_){
    // V columns: transpose 128(tokens) x 64(d) tile through LDS -> vt [bh*64+d][s]
    int hh = (n0 - 2 * D_) >> 6;
    int bb = m0 / S_;
    int bhl = bb * NH_ + hh;
    int sg0 = m0 % S_;
    u16* VhL = (u16*)&Ash[0][0];   // viewed as [64][128]
    u16* VlL = (u16*)&Asl[0][0];
    #pragma unroll
    for (int mi = 0; mi < 2; mi++){
      #pragma unroll
      for (int ni = 0; ni < 4; ni++){
        int d = ni * 16 + cc;
        float bv = bias ? bias[n0 + d] : 0.f;
        int sl = w * 32 + mi * 16 + r4;
        u16x4 h4, l4;
        #pragma unroll
        for (int r = 0; r < 4; r++){
          BfPair p = split_bf(acc[mi][ni][r] + bv);
          h4[r] = p.hi; l4[r] = p.lo;
        }
        *(u16x4*)&VhL[d * 128 + sl] = h4;
        *(u16x4*)&VlL[d * 128 + sl] = l4;
      }
    }
    __syncthreads();
    for (int i = tid; i < 64 * 16; i += 256){
      int d = i >> 4, s8 = (i & 15) * 8;
      size_t go = ((size_t)bhl * DH_ + d) * S_ + sg0 + s8;
      *(u16x8*)&vth[go] = *(const u16x8*)&VhL[d * 128 + s8];
      *(u16x8*)&vtl[go] = *(const u16x8*)&VlL[d * 128 + s8];
    }
    return;
  }
  #pragma unroll
  for (int mi = 0; mi < 2; mi++){
    #pragma unroll
    for (int ni = 0; ni < 4; ni++){
      int col = n0 + ni * 16 + cc;
      float bv = bias ? bias[col] : 0.f;
      #pragma unroll
      for (int r = 0; r < 4; r++){
        int row = m0 + w * 32 + mi * 16 + r4 + r;
        float v = acc[mi][ni][r] + bv;
        if (EPI == 0){
          BfPair p = split_bf(v);
          outh[(size_t)row * N + col] = p.hi;
          outl[(size_t)row * N + col] = p.lo;
        } else {
          outf[(size_t)row * N + col] = v + resid[(size_t)row * N + col];
        }
      }
    }
  }
}

// ------- split-precision flash attention, split-K x3, KVBLK=32, swapped-QK in-reg softmax -------
// grid (bh=24, qb=16, ks=3)
__global__ __launch_bounds__(256) void k_attn3(
    const u16* __restrict__ qkvh, const u16* __restrict__ qkvl,
    const u16* __restrict__ vth, const u16* __restrict__ vtl,
    float* __restrict__ po0, float* __restrict__ po1, float* __restrict__ po2,
    float* __restrict__ pm, float* __restrict__ plsum){
  __shared__ alignas(16) u16 Ksh[2][32 * 64];
  __shared__ alignas(16) u16 Ksl[2][32 * 64];
  __shared__ alignas(16) u16 Vsh[2][64 * 32];
  __shared__ alignas(16) u16 Vsl[2][64 * 32];
  int bh = blockIdx.x, qb = blockIdx.y, ks = blockIdx.z;
  int b = bh / NH_, h = bh % NH_;
  int g = bh * 16 + qb;
  int tid = threadIdx.x, w = tid >> 6, l = tid & 63;
  int q0 = qb * 64 + w * 16;
  const int RS = 3 * D_;
  size_t qoff = (size_t)(b * S_ + q0 + (l & 15)) * RS + h * DH_ + 8 * (l >> 4);
  bf16x8 aqh[2], aql[2];
  aqh[0] = *(const bf16x8*)(qkvh + qoff); aqh[1] = *(const bf16x8*)(qkvh + qoff + 32);
  aql[0] = *(const bf16x8*)(qkvl + qoff); aql[1] = *(const bf16x8*)(qkvl + qoff + 32);
  f32x4 oacc[4];
  #pragma unroll
  for (int i = 0; i < 4; i++) oacc[i] = f32x4{0.f, 0.f, 0.f, 0.f};
  float mrun = -1e30f, lrun = 0.f;

  size_t koff = (size_t)(b * S_ + w * 8 + (l >> 3)) * RS + D_ + h * DH_ + 8 * ((l & 7) ^ (l >> 3));
  const u16* Kgh = qkvh + koff;
  const u16* Kgl = qkvl + koff;
  size_t voff = ((size_t)bh * DH_ + w * 16 + (l >> 2)) * S_ + 8 * ((l & 3) ^ ((l >> 2) & 3));
  const u16* Vgh = vth + voff;
  const u16* Vgl = vtl + voff;
  int wdst = w * 512;

  auto STAGE = [&](int buf, int akt){
    gload_lds16(Kgh + (size_t)(akt * 32) * RS, &Ksh[buf][wdst]);
    gload_lds16(Kgl + (size_t)(akt * 32) * RS, &Ksl[buf][wdst]);
    gload_lds16(Vgh + akt * 32, &Vsh[buf][wdst]);
    gload_lds16(Vgl + akt * 32, &Vsl[buf][wdst]);
  };
  int kt0 = (ks * 32) / KSPLIT;
  int ktE = ((ks + 1) * 32) / KSPLIT;
  STAGE(0, kt0);
  __syncthreads();

  int ck0 = (l >> 4) ^ (l & 7);
  int ck1 = ck0 ^ 4;
  int cv = (l >> 4) ^ (l & 3);
  int s1 = (l & 15) | ((l & 16) << 1);
  int s2 = s1 + 16;
  bool up = (l & 32) != 0;

  for (int kt = kt0; kt < ktE; kt++){
    int cur = (kt - kt0) & 1;
    if (kt + 1 < ktE) STAGE(cur ^ 1, kt + 1);
    f32x4 st[2];
    #pragma unroll
    for (int nt = 0; nt < 2; nt++){
      int rbase = (nt * 16 + (l & 15)) * 64;
      bf16x8 kh0 = *(const bf16x8*)&Ksh[cur][rbase + 8 * ck0];
      bf16x8 kh1 = *(const bf16x8*)&Ksh[cur][rbase + 8 * ck1];
      bf16x8 kl0 = *(const bf16x8*)&Ksl[cur][rbase + 8 * ck0];
      bf16x8 kl1 = *(const bf16x8*)&Ksl[cur][rbase + 8 * ck1];
      f32x4 c = f32x4{0.f, 0.f, 0.f, 0.f};
      c = __builtin_amdgcn_mfma_f32_16x16x32_bf16(kh0, aqh[0], c, 0, 0, 0);
      c = __builtin_amdgcn_mfma_f32_16x16x32_bf16(kh1, aqh[1], c, 0, 0, 0);
      c = __builtin_amdgcn_mfma_f32_16x16x32_bf16(kh0, aql[0], c, 0, 0, 0);
      c = __builtin_amdgcn_mfma_f32_16x16x32_bf16(kh1, aql[1], c, 0, 0, 0);
      c = __builtin_amdgcn_mfma_f32_16x16x32_bf16(kl0, aqh[0], c, 0, 0, 0);
      c = __builtin_amdgcn_mfma_f32_16x16x32_bf16(kl1, aqh[1], c, 0, 0, 0);
      st[nt] = c;
    }
    float mx = fmaxf(fmaxf(fmaxf(st[0][0], st[0][1]), fmaxf(st[0][2], st[0][3])),
                     fmaxf(fmaxf(st[1][0], st[1][1]), fmaxf(st[1][2], st[1][3])));
    mx = fmaxf(mx, __shfl_xor(mx, 16));
    mx = fmaxf(mx, __shfl_xor(mx, 32));
    mx *= 0.125f;
    if (!__all(mx <= mrun)){
      float mnew = fmaxf(mrun, mx);
      float alpha = __expf(mrun - mnew);
      lrun *= alpha;
      #pragma unroll
      for (int r = 0; r < 4; r++){
        float ar = __shfl(alpha, (l & 48) | (((l >> 4) << 2) + r));
        oacc[0][r] *= ar; oacc[1][r] *= ar; oacc[2][r] *= ar; oacc[3][r] *= ar;
      }
      mrun = mnew;
    }
    float p[8]; float sum = 0.f;
    #pragma unroll
    for (int j = 0; j < 8; j++){
      p[j] = __expf(st[j >> 2][j & 3] * 0.125f - mrun);
      sum += p[j];
    }
    sum += __shfl_xor(sum, 16);
    sum += __shfl_xor(sum, 32);
    lrun += sum;
    u32 pkh[4], pkl[4];
    #pragma unroll
    for (int i = 0; i < 4; i++){
      BfPair a = split_bf(p[2 * i]), bb = split_bf(p[2 * i + 1]);
      pkh[i] = (u32)a.hi | ((u32)bb.hi << 16);
      pkl[i] = (u32)a.lo | ((u32)bb.lo << 16);
    }
    u32 ah0 = __shfl((int)pkh[0], s1), ah1 = __shfl((int)pkh[1], s1);
    u32 ah2 = __shfl((int)pkh[2], s1), ah3 = __shfl((int)pkh[3], s1);
    u32 bh0 = __shfl((int)pkh[0], s2), bh1 = __shfl((int)pkh[1], s2);
    u32 bh2 = __shfl((int)pkh[2], s2), bh3 = __shfl((int)pkh[3], s2);
    u32 al0 = __shfl((int)pkl[0], s1), al1 = __shfl((int)pkl[1], s1);
    u32 al2 = __shfl((int)pkl[2], s1), al3 = __shfl((int)pkl[3], s1);
    u32 bl0 = __shfl((int)pkl[0], s2), bl1 = __shfl((int)pkl[1], s2);
    u32 bl2 = __shfl((int)pkl[2], s2), bl3 = __shfl((int)pkl[3], s2);
    u32x4 fh, fl;
    fh.x = up ? ah2 : ah0; fh.y = up ? ah3 : ah1; fh.z = up ? bh2 : bh0; fh.w = up ? bh3 : bh1;
    fl.x = up ? al2 : al0; fl.y = up ? al3 : al1; fl.z = up ? bl2 : bl0; fl.w = up ? bl3 : bl1;
    bf16x8 pa_h = __builtin_bit_cast(bf16x8, fh);
    bf16x8 pa_l = __builtin_bit_cast(bf16x8, fl);
    #pragma unroll
    for (int dt = 0; dt < 4; dt++){
      int vb = (dt * 16 + (l & 15)) * 32 + 8 * cv;
      bf16x8 bvh = *(const bf16x8*)&Vsh[cur][vb];
      bf16x8 bvl = *(const bf16x8*)&Vsl[cur][vb];
      oacc[dt] = __builtin_amdgcn_mfma_f32_16x16x32_bf16(pa_h, bvh, oacc[dt], 0, 0, 0);
      oacc[dt] = __builtin_amdgcn_mfma_f32_16x16x32_bf16(pa_h, bvl, oacc[dt], 0, 0, 0);
      oacc[dt] = __builtin_amdgcn_mfma_f32_16x16x32_bf16(pa_l, bvh, oacc[dt], 0, 0, 0);
    }
    __syncthreads();
  }
  float* po = (ks == 0) ? po0 : ((ks == 1) ? po1 : po2);
  #pragma unroll
  for (int dt = 0; dt < 4; dt++)
    #pragma unroll
    for (int r = 0; r < 4; r++){
      int qloc = w * 16 + (l >> 4) * 4 + r;
      int d = dt * 16 + (l & 15);
      po[((size_t)(g * 64 + qloc)) * 64 + d] = oacc[dt][r];
    }
  if (l < 16){
    pm[(ks * NGRP + g) * 64 + w * 16 + l] = mrun;
    plsum[(ks * NGRP + g) * 64 + w * 16 + l] = lrun;
  }
}

// ---------------- attn split-K merge (3-way) -> split bf16 attn output ----------------
__global__ __launch_bounds__(256) void k_attn_merge(
    const float* __restrict__ po0, const float* __restrict__ po1, const float* __restrict__ po2,
    const float* __restrict__ pm, const float* __restrict__ plsum,
    u16* __restrict__ oh, u16* __restrict__ ol){
  int bh = blockIdx.x, qb = blockIdx.y;
  int b = bh / NH_, h = bh % NH_;
  int g = bh * 16 + qb;
  int t = threadIdx.x;
  int q = t >> 2, d0 = (t & 3) * 16;
  float m0 = pm[g * 64 + q];
  float m1 = pm[(NGRP + g) * 64 + q];
  float m2 = pm[(2 * NGRP + g) * 64 + q];
  float l0 = plsum[g * 64 + q];
  float l1 = plsum[(NGRP + g) * 64 + q];
  float l2 = plsum[(2 * NGRP + g) * 64 + q];
  float M = fmaxf(fmaxf(m0, m1), m2);
  float a0 = __expf(m0 - M), a1 = __expf(m1 - M), a2 = __expf(m2 - M);
  float rcp = 1.f / (l0 * a0 + l1 * a1 + l2 * a2);
  size_t base = ((size_t)(g * 64 + q)) * 64 + d0;
  size_t orow = (size_t)(b * S_ + qb * 64 + q) * D_ + h * DH_ + d0;
  #pragma unroll
  for (int j = 0; j < 16; j++){
    float v = (po0[base + j] * a0 + po1[base + j] * a1 + po2[base + j] * a2) * rcp;
    BfPair p = split_bf(v);
    oh[orow + j] = p.hi;
    ol[orow + j] = p.lo;
  }
}

// ---------------- single-block bucketing ----------------
__global__ __launch_bounds__(1024) void k_bucket(
    const int* __restrict__ flat, int* __restrict__ moeI, int* __restrict__ order){
  __shared__ int cnt[E_], off[E_], cur[E_];
  int t = threadIdx.x;
  if (t < E_){ cnt[t] = 0; cur[t] = 0; }
  __syncthreads();
  int n0 = t, n1 = t + 1024;
  int f0 = flat[n0], f1 = flat[n1];
  atomicAdd(&cnt[f0], 1);
  atomicAdd(&cnt[f1], 1);
  __syncthreads();
  if (t == 0){
    int s = 0;
    for (int e = 0; e < E_; e++){
      off[e] = s; moeI[16 + e] = s; moeI[e] = cnt[e]; s += cnt[e];
    }
  }
  __syncthreads();
  int p0 = atomicAdd(&cur[f0], 1);
  order[off[f0] + p0] = n0;
  int p1 = atomicAdd(&cur[f1], 1);
  order[off[f1] + p1] = n1;
}

// ------- pipelined grouped GEMM 1 (64x64, BK=64, swizzled ^row&7) -------
__global__ __launch_bounds__(256) void k_moe_gemm1(
    const u16* __restrict__ h2, const u16* __restrict__ W1t, const float* __restrict__ b1,
    const int* __restrict__ order, const int* __restrict__ moeI, u16* __restrict__ hid){
  int e = blockIdx.x, mt = blockIdx.y, nt = blockIdx.z;
  int cnt = moeI[e];
  if (mt * 64 >= cnt) return;
  int off = moeI[16 + e];
  __shared__ alignas(16) u16 As[2][64 * 64];
  __shared__ alignas(16) u16 Bs[2][64 * 64];
  int tid = threadIdx.x, w = tid >> 6, l = tid & 63;
  int wr = w >> 1, wc = w & 1;
  f32x4 acc[2][2];
  #pragma unroll
  for (int i = 0; i < 2; i++)
    #pragma unroll
    for (int j = 0; j < 2; j++) acc[i][j] = f32x4{0.f, 0.f, 0.f, 0.f};
  int r0 = w * 16 + (l >> 3);
  int sch = 8 * ((l & 7) ^ (l >> 3));
  int tokA0 = order[off + min(mt * 64 + r0, cnt - 1)];
  int tokA1 = order[off + min(mt * 64 + r0 + 8, cnt - 1)];
  const u16* gA0 = h2 + (size_t)tokA0 * D_ + sch;
  const u16* gA1 = h2 + (size_t)tokA1 * D_ + sch;
  const u16* gB0 = W1t + (size_t)e * HID_ * D_ + (size_t)(nt * 64 + r0) * D_ + sch;
  const u16* gB1 = gB0 + (size_t)8 * D_;
  int d0 = (w * 16) * 64, d1 = (w * 16 + 8) * 64;
  auto STAGE = [&](int buf, int k0){
    gload_lds16(gA0 + k0, &As[buf][d0]);
    gload_lds16(gA1 + k0, &As[buf][d1]);
    gload_lds16(gB0 + k0, &Bs[buf][d0]);
    gload_lds16(gB1 + k0, &Bs[buf][d1]);
  };
  STAGE(0, 0);
  __syncthreads();
  int c0 = (l >> 4) ^ (l & 7);
  int c1 = ((l >> 4) + 4) ^ (l & 7);
  const int nk = D_ / 64;
  for (int t = 0; t < nk; t++){
    int cur = t & 1;
    if (t + 1 < nk) STAGE(cur ^ 1, (t + 1) * 64);
    bf16x8 af[2][2], bfr[2][2];
    #pragma unroll
    for (int mi = 0; mi < 2; mi++){
      int rbase = (wr * 32 + mi * 16 + (l & 15)) * 64;
      af[mi][0] = *(const bf16x8*)&As[cur][rbase + 8 * c0];
      af[mi][1] = *(const bf16x8*)&As[cur][rbase + 8 * c1];
    }
    #pragma unroll
    for (int ni = 0; ni < 2; ni++){
      int rbase = (wc * 32 + ni * 16 + (l & 15)) * 64;
      bfr[ni][0] = *(const bf16x8*)&Bs[cur][rbase + 8 * c0];
      bfr[ni][1] = *(const bf16x8*)&Bs[cur][rbase + 8 * c1];
    }
    #pragma unroll
    for (int mi = 0; mi < 2; mi++)
      #pragma unroll
      for (int ni = 0; ni < 2; ni++){
        acc[mi][ni] = __builtin_amdgcn_mfma_f32_16x16x32_bf16(af[mi][0], bfr[ni][0], acc[mi][ni], 0, 0, 0);
        acc[mi][ni] = __builtin_amdgcn_mfma_f32_16x16x32_bf16(af[mi][1], bfr[ni][1], acc[mi][ni], 0, 0, 0);
      }
    __syncthreads();
  }
  int r4 = (l >> 4) * 4, cc = l & 15;
  #pragma unroll
  for (int mi = 0; mi < 2; mi++){
    #pragma unroll
    for (int ni = 0; ni < 2; ni++){
      int col = nt * 64 + wc * 32 + ni * 16 + cc;
      float bv = b1[e * HID_ + col];
      #pragma unroll
      for (int r = 0; r < 4; r++){
        int rowl = mt * 64 + wr * 32 + mi * 16 + r4 + r;
        if (rowl < cnt){
          float v = gelu_tanh(acc[mi][ni][r] + bv);
          hid[(size_t)(off + rowl) * HID_ + col] = f2bf(v);
        }
      }
    }
  }
}

// ------- pipelined grouped GEMM 2 (64x64, BK=64, swizzled) -------
__global__ __launch_bounds__(256) void k_moe_gemm2(
    const u16* __restrict__ hid, const u16* __restrict__ W2t, const float* __restrict__ b2,
    const int* __restrict__ order, const int* __restrict__ moeI,
    const float* __restrict__ pc, const float* __restrict__ x2, float* __restrict__ out){
  int e = blockIdx.x, mt = blockIdx.y, nt = blockIdx.z;
  int cnt = moeI[e];
  if (mt * 64 >= cnt) return;
  int off = moeI[16 + e];
  __shared__ alignas(16) u16 As[2][64 * 64];
  __shared__ alignas(16) u16 Bs[2][64 * 64];
  int tid = threadIdx.x, w = tid >> 6, l = tid & 63;
  int wr = w >> 1, wc = w & 1;
  f32x4 acc[2][2];
  #pragma unroll
  for (int i = 0; i < 2; i++)
    #pragma unroll
    for (int j = 0; j < 2; j++) acc[i][j] = f32x4{0.f, 0.f, 0.f, 0.f};
  int r0 = w * 16 + (l >> 3);
  int sch = 8 * ((l & 7) ^ (l >> 3));
  int ar0 = off + min(mt * 64 + r0, cnt - 1);
  int ar1 = off + min(mt * 64 + r0 + 8, cnt - 1);
  const u16* gA0 = hid + (size_t)ar0 * HID_ + sch;
  const u16* gA1 = hid + (size_t)ar1 * HID_ + sch;
  const u16* gB0 = W2t + (size_t)e * D_ * HID_ + (size_t)(nt * 64 + r0) * HID_ + sch;
  const u16* gB1 = gB0 + (size_t)8 * HID_;
  int d0 = (w * 16) * 64, d1 = (w * 16 + 8) * 64;
  auto STAGE = [&](int buf, int k0){
    gload_lds16(gA0 + k0, &As[buf][d0]);
    gload_lds16(gA1 + k0, &As[buf][d1]);
    gload_lds16(gB0 + k0, &Bs[buf][d0]);
    gload_lds16(gB1 + k0, &Bs[buf][d1]);
  };
  STAGE(0, 0);
  __syncthreads();
  int c0 = (l >> 4) ^ (l & 7);
  int c1 = ((l >> 4) + 4) ^ (l & 7);
  const int nk = HID_ / 64;
  for (int t = 0; t < nk; t++){
    int cur = t & 1;
    if (t + 1 < nk) STAGE(cur ^ 1, (t + 1) * 64);
    bf16x8 af[2][2], bfr[2][2];
    #pragma unroll
    for (int mi = 0; mi < 2; mi++){
      int rbase = (wr * 32 + mi * 16 + (l & 15)) * 64;
      af[mi][0] = *(const bf16x8*)&As[cur][rbase + 8 * c0];
      af[mi][1] = *(const bf16x8*)&As[cur][rbase + 8 * c1];
    }
    #pragma unroll
    for (int ni = 0; ni < 2; ni++){
      int rbase = (wc * 32 + ni * 16 + (l & 15)) * 64;
      bfr[ni][0] = *(const bf16x8*)&Bs[cur][rbase + 8 * c0];
      bfr[ni][1] = *(const bf16x8*)&Bs[cur][rbase + 8 * c1];
    }
    #pragma unroll
    for (int mi = 0; mi < 2; mi++)
      #pragma unroll
      for (int ni = 0; ni < 2; ni++){
        acc[mi][ni] = __builtin_amdgcn_mfma_f32_16x16x32_bf16(af[mi][0], bfr[ni][0], acc[mi][ni], 0, 0, 0);
        acc[mi][ni] = __builtin_amdgcn_mfma_f32_16x16x32_bf16(af[mi][1], bfr[ni][1], acc[mi][ni], 0, 0, 0);
      }
    __syncthreads();
  }
  int r4 = (l >> 4) * 4, cc = l & 15;
  #pragma unroll
  for (int mi = 0; mi < 2; mi++){
    #pragma unroll
    for (int r = 0; r < 4; r++){
      int rowl = mt * 64 + wr * 32 + mi * 16 + r4 + r;
      if (rowl < cnt){
        int tok = order[off + rowl];
        float pv = pc[tok];
        #pragma unroll
        for (int ni = 0; ni < 2; ni++){
          int col = nt * 64 + wc * 32 + ni * 16 + cc;
          float v = acc[mi][ni][r] + b2[e * D_ + col];
          out[(size_t)tok * D_ + col] = x2[(size_t)tok * D_ + col] + pv * v;
        }
      }
    }
  }
}

extern "C" void kernel_launch(void* const* d_in, const int* in_sizes, int n_in,
                              void* d_out, int out_size, void* d_ws, size_t ws_size,
                              hipStream_t stream){
  const float* x         = (const float*)d_in[0];
  const float* ln1_w     = (const float*)d_in[1];
  const float* ln1_b     = (const float*)d_in[2];
  const float* in_proj_w = (const float*)d_in[3];
  const float* in_proj_b = (const float*)d_in[4];
  const float* out_proj_w= (const float*)d_in[5];
  const float* out_proj_b= (const float*)d_in[6];
  const float* ln2_w     = (const float*)d_in[7];
  const float* ln2_b     = (const float*)d_in[8];
  const float* Wg        = (const float*)d_in[9];
  const float* bg        = (const float*)d_in[10];
  const float* We        = (const float*)d_in[11];
  const float* be        = (const float*)d_in[12];
  const float* W1        = (const float*)d_in[13];
  const float* b1        = (const float*)d_in[14];
  const float* W2        = (const float*)d_in[15];
  const float* b2        = (const float*)d_in[16];
  float* out = (float*)d_out;

  char* ws = (char*)d_ws;
  size_t off = 0;
  auto alloc = [&](size_t bytes) -> char* {
    char* p = ws + off;
    off += (bytes + 255) & ~(size_t)255;
    return p;
  };
  u16*   inpTh = (u16*)  alloc((size_t)3 * D_ * D_ * 2);
  u16*   inpTl = (u16*)  alloc((size_t)3 * D_ * D_ * 2);
  u16*   outpTh= (u16*)  alloc((size_t)D_ * D_ * 2);
  u16*   outpTl= (u16*)  alloc((size_t)D_ * D_ * 2);
  u16*   W1t  = (u16*)  alloc((size_t)E_ * HID_ * D_ * 2);
  u16*   W2t  = (u16*)  alloc((size_t)E_ * D_ * HID_ * 2);
  u16*   qkvh = (u16*)  alloc((size_t)NTOK * 3 * D_ * 2);
  u16*   qkvl = (u16*)  alloc((size_t)NTOK * 3 * D_ * 2);
  u16*   h1h  = (u16*)  alloc((size_t)NTOK * D_ * 2);
  u16*   h1l  = (u16*)  alloc((size_t)NTOK * D_ * 2);
  u16*   vth  = (u16*)  alloc((size_t)B_ * NH_ * DH_ * S_ * 2);
  u16*   vtl  = (u16*)  alloc((size_t)B_ * NH_ * DH_ * S_ * 2);
  float* x2   = (float*)alloc((size_t)NTOK * D_ * 4);
  u16*   h2   = (u16*)  alloc((size_t)NTOK * D_ * 2);
  int*   flat = (int*)  alloc(NTOK * 4);
  float* pc   = (float*)alloc(NTOK * 4);
  int*   order= (int*)  alloc(NTOK * 4);
  int*   moeI = (int*)  alloc(32 * 4);
  // aliases (lifetimes disjoint):
  float* po0  = (float*)h1h;                       // over h1h+h1l (dead after QKV)
  float* po1  = (float*)inpTh;                     // over inpTh+inpTl (dead after QKV)
  float* po2  = x2;                                // x2 written only later by out-proj
  float* pmArr= (float*)((char*)inpTh + 6291456);
  float* plArr= (float*)((char*)inpTh + 6291456 + 294912);
  u16*   attnh= qkvh;
  u16*   attnl= qkvl;
  u16*   hid  = (u16*)qkvl;

  // fused weight prep
  k_prep<<<dim3(20736), dim3(256), 0, stream>>>(
      in_proj_w, out_proj_w, W1, W2, inpTh, inpTl, outpTh, outpTl, W1t, W2t);
  // LN1 (split output, no router)
  k_layernorm<0><<<dim3(NTOK), dim3(256), 0, stream>>>(
      x, ln1_w, ln1_b, h1h, h1l, nullptr, nullptr, nullptr, nullptr, nullptr, nullptr);
  // QKV (split GEMM, 128x64 tile; V columns transposed directly into vt)
  k_gemm3<0><<<dim3(NTOK / 128, 3 * D_ / 64), dim3(256), 0, stream>>>(
      h1h, h1l, inpTh, inpTl, in_proj_b, nullptr, qkvh, qkvl, nullptr, vth, vtl, NTOK, 3 * D_, D_);
  // attention split-K x3 partials (QBLK=64, LDS-staged)
  k_attn3<<<dim3(B_ * NH_, S_ / 64, KSPLIT), dim3(256), 0, stream>>>(
      qkvh, qkvl, vth, vtl, po0, po1, po2, pmArr, plArr);
  // merge thirds -> split bf16 attn (into qkv region)
  k_attn_merge<<<dim3(B_ * NH_, S_ / 64), dim3(256), 0, stream>>>(
      po0, po1, po2, pmArr, plArr, attnh, attnl);
  // out-proj + residual -> x2 (f32)
  k_gemm3<1><<<dim3(NTOK / 128, D_ / 64), dim3(256), 0, stream>>>(
      attnh, attnl, outpTh, outpTl, out_proj_b, x, nullptr, nullptr, x2,
      (u16*)nullptr, (u16*)nullptr, NTOK, D_, D_);
  // LN2 + fused router: bf16 hi for MoE + flat/pc
  k_layernorm<1><<<dim3(NTOK), dim3(256), 0, stream>>>(
      x2, ln2_w, ln2_b, h2, nullptr, Wg, bg, We, be, flat, pc);
  // bucketing
  k_bucket<<<dim3(1), dim3(1024), 0, stream>>>(flat, moeI, order);
  // grouped expert GEMMs (e = blockIdx.x -> XCD pin)
  k_moe_gemm1<<<dim3(E_, NTOK / 64, HID_ / 64), dim3(256), 0, stream>>>(h2, W1t, b1, order, moeI, hid);
  k_moe_gemm2<<<dim3(E_, NTOK / 64, D_ / 64), dim3(256), 0, stream>>>(hid, W2t, b2, order, moeI, pc, x2, out);
}